// Round 1
// baseline (7677.459 us; speedup 1.0000x reference)
//
#include <hip/hip_runtime.h>

#define N_NODES 100000
#define N_EDGES 600000
#define HIDDEN 128
#define N_LAYERS 4

// ---------------------------------------------------------------------------
// Transpose per-layer weights: Wt[l][m][k] = Ws[l][k][m]  (so GEMM k-loop is
// contiguous per output column -> float4 loads)
// ---------------------------------------------------------------------------
__global__ void transpose_W(const float* __restrict__ Ws, float* __restrict__ Wt) {
    int idx = blockIdx.x * blockDim.x + threadIdx.x;
    if (idx >= N_LAYERS * HIDDEN * HIDDEN) return;
    int l = idx / (HIDDEN * HIDDEN);
    int r = idx % (HIDDEN * HIDDEN);
    int k = r / HIDDEN, m = r % HIDDEN;
    Wt[(size_t)l * HIDDEN * HIDDEN + (size_t)m * HIDDEN + k] = Ws[idx];
}

// ---------------------------------------------------------------------------
// h[n][c] = sum_k x[n][k] * W[k][c] + b[c]   (thread per output element,
// k-loop float4-vectorized via transposed W; W rows live in L1/L2)
// ---------------------------------------------------------------------------
__global__ void gemm_bias(const float* __restrict__ x, const float* __restrict__ Wt,
                          const float* __restrict__ b, float* __restrict__ h) {
    int gid = blockIdx.x * blockDim.x + threadIdx.x;
    if (gid >= N_NODES * HIDDEN) return;
    int n = gid >> 7;
    int c = gid & (HIDDEN - 1);
    const float4* xr = (const float4*)(x + (size_t)n * HIDDEN);
    const float4* wr = (const float4*)(Wt + (size_t)c * HIDDEN);
    float acc = b[c];
    #pragma unroll 8
    for (int k4 = 0; k4 < HIDDEN / 4; ++k4) {
        float4 a = xr[k4];
        float4 wv = wr[k4];
        acc += a.x * wv.x + a.y * wv.y + a.z * wv.z + a.w * wv.w;
    }
    h[gid] = acc;
}

// ---------------------------------------------------------------------------
// Edge scatter: xnew[dst[e]][:] += h[src[e]][:] * w[e]
// 32 lanes per edge, float4 per lane, 4 f32 atomics per lane.
// ---------------------------------------------------------------------------
__global__ void scatter_edges(const float* __restrict__ h, const int* __restrict__ src,
                              const int* __restrict__ dst, const float* __restrict__ w,
                              float* __restrict__ xnew) {
    long long tid = (long long)blockIdx.x * blockDim.x + threadIdx.x;
    int e = (int)(tid >> 5);
    if (e >= N_EDGES) return;
    int lane4 = (int)(tid & 31);
    int s = src[e];
    int d = dst[e];
    float we = w[e];
    float4 m = ((const float4*)(h + (size_t)s * HIDDEN))[lane4];
    float* out = xnew + (size_t)d * HIDDEN + lane4 * 4;
    atomicAdd(out + 0, m.x * we);
    atomicAdd(out + 1, m.y * we);
    atomicAdd(out + 2, m.z * we);
    atomicAdd(out + 3, m.w * we);
}

// ---------------------------------------------------------------------------
// Fused (optional leaky-relu, in place) + energy tap:
//   energy[n] (=|+=) (dot(x[n], We_l) + be_l) * temp_l
// One 64-lane wave per node, float2 per lane, shfl_xor reduce.
// DO_RELU: apply leaky relu and write back. MODE 0: energy =, MODE 1: energy +=
// ---------------------------------------------------------------------------
template <int DO_RELU, int MODE>
__global__ void relu_tap(const float* __restrict__ xin, float* __restrict__ xout,
                         const float* __restrict__ We_l, const float* __restrict__ be_l,
                         const float* __restrict__ temp_l, float* __restrict__ energy) {
    int gtid = blockIdx.x * blockDim.x + threadIdx.x;
    int wid = gtid >> 6;          // node index
    int lane = gtid & 63;
    if (wid >= N_NODES) return;
    float2 v = ((const float2*)(xin + (size_t)wid * HIDDEN))[lane];
    if (DO_RELU) {
        v.x = v.x > 0.f ? v.x : 0.01f * v.x;
        v.y = v.y > 0.f ? v.y : 0.01f * v.y;
        ((float2*)(xout + (size_t)wid * HIDDEN))[lane] = v;
    }
    float2 we2 = ((const float2*)We_l)[lane];
    float acc = v.x * we2.x + v.y * we2.y;
    #pragma unroll
    for (int off = 32; off > 0; off >>= 1) acc += __shfl_xor(acc, off);
    if (lane == 0) {
        float ev = (acc + be_l[0]) * temp_l[0];
        if (MODE == 0) energy[wid] = ev;
        else           energy[wid] += ev;
    }
}

extern "C" void kernel_launch(void* const* d_in, const int* in_sizes, int n_in,
                              void* d_out, int out_size, void* d_ws, size_t ws_size,
                              hipStream_t stream) {
    const float* x    = (const float*)d_in[0];
    const int*   src  = (const int*)d_in[1];
    const int*   dst  = (const int*)d_in[2];
    const float* w    = (const float*)d_in[3];
    const float* Ws   = (const float*)d_in[4];
    const float* bs   = (const float*)d_in[5];
    const float* We   = (const float*)d_in[6];
    const float* be   = (const float*)d_in[7];
    const float* temp = (const float*)d_in[8];

    float* energy = (float*)d_out;              // [N]
    float* xout   = (float*)d_out + N_NODES;    // [N,128] (scatter target / final x)

    float* Wt = (float*)d_ws;                           // 4*128*128
    float* h  = Wt + (size_t)N_LAYERS * HIDDEN * HIDDEN; // [N,128]

    // Prepare transposed weights
    transpose_W<<<(N_LAYERS * HIDDEN * HIDDEN + 255) / 256, 256, 0, stream>>>(Ws, Wt);

    // energy tap 0 on the raw input x
    {
        int threads = N_NODES * 64;
        relu_tap<0, 0><<<(threads + 255) / 256, 256, 0, stream>>>(
            x, nullptr, We, be, temp, energy);
    }

    const float* xcur = x;
    for (int i = 0; i < N_LAYERS; ++i) {
        // h = xcur @ W_i + b_i
        gemm_bias<<<(N_NODES * HIDDEN + 255) / 256, 256, 0, stream>>>(
            xcur, Wt + (size_t)i * HIDDEN * HIDDEN, bs + (size_t)i * HIDDEN, h);

        // xnew = 0
        hipMemsetAsync(xout, 0, (size_t)N_NODES * HIDDEN * sizeof(float), stream);

        // xnew[dst] += h[src] * w
        {
            long long threads = (long long)N_EDGES * 32;
            int blocks = (int)((threads + 255) / 256);
            scatter_edges<<<blocks, 256, 0, stream>>>(h, src, dst, w, xout);
        }

        // leaky relu in place + energy tap i+1
        {
            int threads = N_NODES * 64;
            relu_tap<1, 1><<<(threads + 255) / 256, 256, 0, stream>>>(
                xout, xout, We + (size_t)(i + 1) * HIDDEN, be + (i + 1), temp + (i + 1), energy);
        }
        xcur = xout;
    }
}

// Round 2
// 1062.366 us; speedup vs baseline: 7.2268x; 7.2268x over previous
//
#include <hip/hip_runtime.h>

#define N_NODES 100000
#define N_EDGES 600000
#define HIDDEN 128
#define N_LAYERS 4

// ===========================================================================
// CSR build: count -> exclusive scan -> fill (src,w) in CSR-by-dst order
// ===========================================================================
__global__ void count_dst(const int* __restrict__ dst, int* __restrict__ cnt) {
    int e = blockIdx.x * blockDim.x + threadIdx.x;
    if (e >= N_EDGES) return;
    atomicAdd(&cnt[dst[e]], 1);
}

// pass 1: per-1024-element block exclusive scan, emit block sums
__global__ void scan1(const int* __restrict__ cnt, int* __restrict__ excl,
                      int* __restrict__ bsums, int n) {
    __shared__ int lds[8];
    int t = threadIdx.x;
    int base = blockIdx.x * 1024 + t * 4;
    int v0 = (base + 0 < n) ? cnt[base + 0] : 0;
    int v1 = (base + 1 < n) ? cnt[base + 1] : 0;
    int v2 = (base + 2 < n) ? cnt[base + 2] : 0;
    int v3 = (base + 3 < n) ? cnt[base + 3] : 0;
    int tsum = v0 + v1 + v2 + v3;
    int lane = t & 63, wv = t >> 6;
    int s = tsum;
    #pragma unroll
    for (int off = 1; off < 64; off <<= 1) {
        int u = __shfl_up(s, off);
        if (lane >= off) s += u;
    }
    if (lane == 63) lds[wv] = s;
    __syncthreads();
    if (t == 0) {
        int a = 0;
        #pragma unroll
        for (int i = 0; i < 4; ++i) { int bb = lds[i]; lds[i] = a; a += bb; }
        lds[4] = a;
    }
    __syncthreads();
    int excl_t = (s - tsum) + lds[wv];
    if (base + 0 < n) excl[base + 0] = excl_t;
    if (base + 1 < n) excl[base + 1] = excl_t + v0;
    if (base + 2 < n) excl[base + 2] = excl_t + v0 + v1;
    if (base + 3 < n) excl[base + 3] = excl_t + v0 + v1 + v2;
    if (t == 0) bsums[blockIdx.x] = lds[4];
}

// pass 2: exclusive scan of <=256 block sums, single block of 256
__global__ void scan2(int* __restrict__ bsums, int nb) {
    __shared__ int wsum[4];
    int t = threadIdx.x;
    int v = (t < nb) ? bsums[t] : 0;
    int lane = t & 63, wv = t >> 6;
    int s = v;
    #pragma unroll
    for (int off = 1; off < 64; off <<= 1) {
        int u = __shfl_up(s, off);
        if (lane >= off) s += u;
    }
    if (lane == 63) wsum[wv] = s;
    __syncthreads();
    int add = 0;
    for (int i = 0; i < wv; ++i) add += wsum[i];
    if (t < nb) bsums[t] = (s - v) + add;
}

// pass 3: rowptr[i] = excl[i] + bsums[block(i)]; rowptr[n] = E
__global__ void scan3(const int* __restrict__ excl, const int* __restrict__ bsums,
                      int* __restrict__ rowptr, int n) {
    int i = blockIdx.x * blockDim.x + threadIdx.x;
    if (i < n) rowptr[i] = excl[i] + bsums[i >> 10];
    else if (i == n) rowptr[n] = N_EDGES;
}

__global__ void fill_csr(const int* __restrict__ src, const int* __restrict__ dst,
                         const float* __restrict__ w, const int* __restrict__ rowptr,
                         int* __restrict__ fillc, int* __restrict__ es,
                         float* __restrict__ ew) {
    int e = blockIdx.x * blockDim.x + threadIdx.x;
    if (e >= N_EDGES) return;
    int d = dst[e];
    int pos = atomicAdd(&fillc[d], 1);
    int slot = rowptr[d] + pos;
    es[slot] = src[e];
    ew[slot] = w[e];
}

// ===========================================================================
// GEMM: h[n][c] = x[n][:] @ W[:][c] + b[c]
// Block: 256 threads, 64 nodes x 128 cols. W (128x128 f32, [k][c]) in LDS.
// Thread micro-tile: 8 nodes x 4 cols -> 128 FMA per (8 global + 4 LDS) loads.
// ===========================================================================
__global__ __launch_bounds__(256) void gemm_tiled(const float* __restrict__ x,
                                                  const float* __restrict__ W,
                                                  const float* __restrict__ b,
                                                  float* __restrict__ h) {
    __shared__ float4 sW[128 * 32];  // [k][c/4], 64 KB
    int t = threadIdx.x;
    const float4* Wg = (const float4*)W;
    #pragma unroll
    for (int j = 0; j < 16; ++j) sW[t + j * 256] = Wg[t + j * 256];
    __syncthreads();

    int tx = t & 31;   // col group: cols tx*4 .. tx*4+3
    int ty = t >> 5;   // node group: rows ty*8 .. ty*8+7
    int row0 = blockIdx.x * 64 + ty * 8;

    float4 bias = ((const float4*)b)[tx];
    float4 acc[8];
    #pragma unroll
    for (int i = 0; i < 8; ++i) acc[i] = bias;

    const float4* xr[8];
    bool valid[8];
    #pragma unroll
    for (int i = 0; i < 8; ++i) {
        int r = row0 + i;
        valid[i] = (r < N_NODES);
        xr[i] = (const float4*)(x + (size_t)r * HIDDEN);
    }

    for (int k4 = 0; k4 < 32; ++k4) {
        float4 xv[8];
        #pragma unroll
        for (int i = 0; i < 8; ++i)
            xv[i] = valid[i] ? xr[i][k4] : float4{0.f, 0.f, 0.f, 0.f};
        #pragma unroll
        for (int kk = 0; kk < 4; ++kk) {
            float4 wv = sW[(k4 * 4 + kk) * 32 + tx];
            #pragma unroll
            for (int i = 0; i < 8; ++i) {
                float xs = (kk == 0) ? xv[i].x : (kk == 1) ? xv[i].y
                         : (kk == 2) ? xv[i].z : xv[i].w;
                acc[i].x += xs * wv.x;
                acc[i].y += xs * wv.y;
                acc[i].z += xs * wv.z;
                acc[i].w += xs * wv.w;
            }
        }
    }
    #pragma unroll
    for (int i = 0; i < 8; ++i)
        if (valid[i]) ((float4*)(h + (size_t)(row0 + i) * HIDDEN))[tx] = acc[i];
}

// ===========================================================================
// Fused aggregation (CSR pull) + leaky-relu + energy tap.
// One 64-lane wave per node; float2 per lane holds the 128-float row.
// ===========================================================================
__global__ void agg_relu_tap(const float* __restrict__ h, const int* __restrict__ rowptr,
                             const int* __restrict__ es, const float* __restrict__ ew,
                             const float* __restrict__ We_l, const float* __restrict__ be_l,
                             const float* __restrict__ temp_l,
                             float* __restrict__ xout, float* __restrict__ energy) {
    int gtid = blockIdx.x * blockDim.x + threadIdx.x;
    int n = gtid >> 6, lane = gtid & 63;
    if (n >= N_NODES) return;
    int j0 = rowptr[n], j1 = rowptr[n + 1];
    float2 acc = {0.f, 0.f};
    for (int j = j0; j < j1; ++j) {
        int s = es[j];
        float we = ew[j];
        float2 v = ((const float2*)(h + (size_t)s * HIDDEN))[lane];
        acc.x += v.x * we;
        acc.y += v.y * we;
    }
    acc.x = acc.x > 0.f ? acc.x : 0.01f * acc.x;
    acc.y = acc.y > 0.f ? acc.y : 0.01f * acc.y;
    ((float2*)(xout + (size_t)n * HIDDEN))[lane] = acc;

    float2 we2 = ((const float2*)We_l)[lane];
    float dot = acc.x * we2.x + acc.y * we2.y;
    #pragma unroll
    for (int off = 32; off > 0; off >>= 1) dot += __shfl_xor(dot, off);
    if (lane == 0) energy[n] += (dot + be_l[0]) * temp_l[0];
}

// Energy tap 0 on raw input x (no relu, energy =)
__global__ void tap0(const float* __restrict__ xin, const float* __restrict__ We_l,
                     const float* __restrict__ be_l, const float* __restrict__ temp_l,
                     float* __restrict__ energy) {
    int gtid = blockIdx.x * blockDim.x + threadIdx.x;
    int n = gtid >> 6, lane = gtid & 63;
    if (n >= N_NODES) return;
    float2 v = ((const float2*)(xin + (size_t)n * HIDDEN))[lane];
    float2 we2 = ((const float2*)We_l)[lane];
    float dot = v.x * we2.x + v.y * we2.y;
    #pragma unroll
    for (int off = 32; off > 0; off >>= 1) dot += __shfl_xor(dot, off);
    if (lane == 0) energy[n] = (dot + be_l[0]) * temp_l[0];
}

extern "C" void kernel_launch(void* const* d_in, const int* in_sizes, int n_in,
                              void* d_out, int out_size, void* d_ws, size_t ws_size,
                              hipStream_t stream) {
    const float* x    = (const float*)d_in[0];
    const int*   src  = (const int*)d_in[1];
    const int*   dst  = (const int*)d_in[2];
    const float* w    = (const float*)d_in[3];
    const float* Ws   = (const float*)d_in[4];
    const float* bs   = (const float*)d_in[5];
    const float* We   = (const float*)d_in[6];
    const float* be   = (const float*)d_in[7];
    const float* temp = (const float*)d_in[8];

    float* energy = (float*)d_out;            // [N]
    float* xout   = (float*)d_out + N_NODES;  // [N,128]

    // workspace layout
    float* h      = (float*)d_ws;                       // 12.8M f32
    int*   cnt    = (int*)(h + (size_t)N_NODES * HIDDEN);
    int*   excl   = cnt + N_NODES;
    int*   bsums  = excl + N_NODES;                     // 128
    int*   rowptr = bsums + 128;                        // N+1
    int*   fillc  = rowptr + (N_NODES + 1);
    int*   es     = fillc + N_NODES;                    // E
    float* ew     = (float*)(es + N_EDGES);             // E

    // ---- CSR build (once; reused across layers) ----
    hipMemsetAsync(cnt, 0, N_NODES * sizeof(int), stream);
    count_dst<<<(N_EDGES + 255) / 256, 256, 0, stream>>>(dst, cnt);
    int nblk = (N_NODES + 1023) / 1024;  // 98
    scan1<<<nblk, 256, 0, stream>>>(cnt, excl, bsums, N_NODES);
    scan2<<<1, 256, 0, stream>>>(bsums, nblk);
    scan3<<<(N_NODES + 1 + 255) / 256, 256, 0, stream>>>(excl, bsums, rowptr, N_NODES);
    hipMemsetAsync(fillc, 0, N_NODES * sizeof(int), stream);
    fill_csr<<<(N_EDGES + 255) / 256, 256, 0, stream>>>(src, dst, w, rowptr, fillc, es, ew);

    // ---- energy tap 0 ----
    tap0<<<(N_NODES * 64) / 256, 256, 0, stream>>>(x, We, be, temp, energy);

    // ---- layers ----
    const float* xcur = x;
    for (int i = 0; i < N_LAYERS; ++i) {
        gemm_tiled<<<(N_NODES + 63) / 64, 256, 0, stream>>>(
            xcur, Ws + (size_t)i * HIDDEN * HIDDEN, bs + (size_t)i * HIDDEN, h);
        agg_relu_tap<<<(N_NODES * 64) / 256, 256, 0, stream>>>(
            h, rowptr, es, ew, We + (size_t)(i + 1) * HIDDEN, be + (i + 1),
            temp + (i + 1), xout, energy);
        xcur = xout;
    }
}

// Round 3
// 533.777 us; speedup vs baseline: 14.3833x; 1.9903x over previous
//
#include <hip/hip_runtime.h>
#include <hip/hip_bf16.h>

#define N_NODES 100000
#define N_EDGES 600000
#define HIDDEN 128
#define N_LAYERS 4
#define MPAD 100096   // N_NODES rounded up to 128

typedef short bf16x8 __attribute__((ext_vector_type(8)));
typedef float f32x4 __attribute__((ext_vector_type(4)));

__device__ inline ushort f2bf(float f) {
    __hip_bfloat16 h = __float2bfloat16(f);
    return *reinterpret_cast<ushort*>(&h);
}

// ===========================================================================
// CSR build: count -> exclusive scan -> fill (src,w) in CSR-by-dst order
// ===========================================================================
__global__ void count_dst(const int* __restrict__ dst, int* __restrict__ cnt) {
    int e = blockIdx.x * blockDim.x + threadIdx.x;
    if (e >= N_EDGES) return;
    atomicAdd(&cnt[dst[e]], 1);
}

__global__ void scan1(const int* __restrict__ cnt, int* __restrict__ excl,
                      int* __restrict__ bsums, int n) {
    __shared__ int lds[8];
    int t = threadIdx.x;
    int base = blockIdx.x * 1024 + t * 4;
    int v0 = (base + 0 < n) ? cnt[base + 0] : 0;
    int v1 = (base + 1 < n) ? cnt[base + 1] : 0;
    int v2 = (base + 2 < n) ? cnt[base + 2] : 0;
    int v3 = (base + 3 < n) ? cnt[base + 3] : 0;
    int tsum = v0 + v1 + v2 + v3;
    int lane = t & 63, wv = t >> 6;
    int s = tsum;
    #pragma unroll
    for (int off = 1; off < 64; off <<= 1) {
        int u = __shfl_up(s, off);
        if (lane >= off) s += u;
    }
    if (lane == 63) lds[wv] = s;
    __syncthreads();
    if (t == 0) {
        int a = 0;
        #pragma unroll
        for (int i = 0; i < 4; ++i) { int bb = lds[i]; lds[i] = a; a += bb; }
        lds[4] = a;
    }
    __syncthreads();
    int excl_t = (s - tsum) + lds[wv];
    if (base + 0 < n) excl[base + 0] = excl_t;
    if (base + 1 < n) excl[base + 1] = excl_t + v0;
    if (base + 2 < n) excl[base + 2] = excl_t + v0 + v1;
    if (base + 3 < n) excl[base + 3] = excl_t + v0 + v1 + v2;
    if (t == 0) bsums[blockIdx.x] = lds[4];
}

__global__ void scan2(int* __restrict__ bsums, int nb) {
    __shared__ int wsum[4];
    int t = threadIdx.x;
    int v = (t < nb) ? bsums[t] : 0;
    int lane = t & 63, wv = t >> 6;
    int s = v;
    #pragma unroll
    for (int off = 1; off < 64; off <<= 1) {
        int u = __shfl_up(s, off);
        if (lane >= off) s += u;
    }
    if (lane == 63) wsum[wv] = s;
    __syncthreads();
    int add = 0;
    for (int i = 0; i < wv; ++i) add += wsum[i];
    if (t < nb) bsums[t] = (s - v) + add;
}

__global__ void scan3(const int* __restrict__ excl, const int* __restrict__ bsums,
                      int* __restrict__ rowptr, int n) {
    int i = blockIdx.x * blockDim.x + threadIdx.x;
    if (i < n) rowptr[i] = excl[i] + bsums[i >> 10];
    else if (i == n) rowptr[n] = N_EDGES;
}

__global__ void fill_csr(const int* __restrict__ src, const int* __restrict__ dst,
                         const float* __restrict__ w, const int* __restrict__ rowptr,
                         int* __restrict__ fillc, int* __restrict__ es,
                         float* __restrict__ ew) {
    int e = blockIdx.x * blockDim.x + threadIdx.x;
    if (e >= N_EDGES) return;
    int d = dst[e];
    int pos = atomicAdd(&fillc[d], 1);
    int slot = rowptr[d] + pos;
    es[slot] = src[e];
    ew[slot] = w[e];
}

// ===========================================================================
// Weight prep: whi/wlo[l][c][k] = split_bf16(Ws[l][k][c])  (transposed layout)
// ===========================================================================
__global__ void prep_w(const float* __restrict__ Ws, ushort* __restrict__ whi,
                       ushort* __restrict__ wlo) {
    int idx = blockIdx.x * blockDim.x + threadIdx.x;
    if (idx >= N_LAYERS * HIDDEN * HIDDEN) return;
    int l = idx >> 14;
    int r = idx & 16383;
    int c = r >> 7, k = r & 127;
    float v = Ws[(l << 14) + k * HIDDEN + c];
    ushort hi = f2bf(v);
    float hif = __uint_as_float(((uint)hi) << 16);
    ushort lo = f2bf(v - hif);
    whi[idx] = hi;
    wlo[idx] = lo;
}

// ===========================================================================
// tap0 + cast x0 -> (xhi, xlo) bf16 split. One wave per node.
// ===========================================================================
__global__ void tap0_cast(const float* __restrict__ x, const float* __restrict__ We_l,
                          const float* __restrict__ be_l, const float* __restrict__ temp_l,
                          float* __restrict__ energy, uint* __restrict__ xhi,
                          uint* __restrict__ xlo) {
    int gtid = blockIdx.x * blockDim.x + threadIdx.x;
    int n = gtid >> 6, lane = gtid & 63;
    if (n >= N_NODES) return;
    float2 v = ((const float2*)(x + (size_t)n * HIDDEN))[lane];
    // split cast
    ushort hx = f2bf(v.x), hy = f2bf(v.y);
    float hxf = __uint_as_float(((uint)hx) << 16);
    float hyf = __uint_as_float(((uint)hy) << 16);
    ushort lx = f2bf(v.x - hxf), ly = f2bf(v.y - hyf);
    xhi[(size_t)n * 64 + lane] = (uint)hx | ((uint)hy << 16);
    xlo[(size_t)n * 64 + lane] = (uint)lx | ((uint)ly << 16);
    // tap
    float2 we2 = ((const float2*)We_l)[lane];
    float dot = v.x * we2.x + v.y * we2.y;
    #pragma unroll
    for (int off = 32; off > 0; off >>= 1) dot += __shfl_xor(dot, off);
    if (lane == 0) energy[n] = (dot + be_l[0]) * temp_l[0];
}

// ===========================================================================
// GEMM via split-bf16 MFMA (3 products: hi*hi + hi*lo + lo*hi).
// Swapped operands: A = W^T fragments, B = x^T fragments, so each lane's D
// holds h[node][c..c+3] contiguous -> float4 store.
// Block: 256 thr / 4 waves; 128 nodes x 128 cols; wave w -> cols [w*32, w*32+32).
// No LDS: W frags are L1-hot across blocks, x frags L2-fed.
// ===========================================================================
__global__ __launch_bounds__(256) void gemm_mfma_split(
    const uint* __restrict__ xhi, const uint* __restrict__ xlo,
    const ushort* __restrict__ whi, const ushort* __restrict__ wlo,
    const float* __restrict__ b, float* __restrict__ h) {
    int t = threadIdx.x;
    int lane = t & 63, wv = t >> 6;
    int l15 = lane & 15, l4 = lane >> 4;
    int row0 = blockIdx.x * 128;
    int c0 = wv * 32;

    // A fragments (W side), hoisted: [m][s]
    bf16x8 Ah[2][4], Al[2][4];
    #pragma unroll
    for (int m = 0; m < 2; ++m) {
        int c = c0 + m * 16 + l15;
        #pragma unroll
        for (int s = 0; s < 4; ++s) {
            int off = c * HIDDEN + s * 32 + l4 * 8;
            Ah[m][s] = *(const bf16x8*)(whi + off);
            Al[m][s] = *(const bf16x8*)(wlo + off);
        }
    }

    f32x4 acc[2][8];
    #pragma unroll
    for (int m = 0; m < 2; ++m)
        #pragma unroll
        for (int n = 0; n < 8; ++n)
            acc[m][n] = f32x4{0.f, 0.f, 0.f, 0.f};

    #pragma unroll
    for (int n = 0; n < 8; ++n) {
        int node = row0 + n * 16 + l15;
        if (node >= N_NODES) node = N_NODES - 1;   // xhi/xlo are unpadded
        const ushort* xh = (const ushort*)xhi + (size_t)node * HIDDEN;
        const ushort* xl = (const ushort*)xlo + (size_t)node * HIDDEN;
        #pragma unroll
        for (int s = 0; s < 4; ++s) {
            bf16x8 bh = *(const bf16x8*)(xh + s * 32 + l4 * 8);
            bf16x8 bl = *(const bf16x8*)(xl + s * 32 + l4 * 8);
            #pragma unroll
            for (int m = 0; m < 2; ++m) {
                acc[m][n] = __builtin_amdgcn_mfma_f32_16x16x32_bf16(Ah[m][s], bh, acc[m][n], 0, 0, 0);
                acc[m][n] = __builtin_amdgcn_mfma_f32_16x16x32_bf16(Ah[m][s], bl, acc[m][n], 0, 0, 0);
                acc[m][n] = __builtin_amdgcn_mfma_f32_16x16x32_bf16(Al[m][s], bh, acc[m][n], 0, 0, 0);
            }
        }
    }

    // Epilogue: +bias, store f32 h (padded to MPAD rows, store unguarded)
    #pragma unroll
    for (int m = 0; m < 2; ++m) {
        f32x4 bias = *(const f32x4*)(b + c0 + m * 16 + l4 * 4);
        #pragma unroll
        for (int n = 0; n < 8; ++n) {
            int node = row0 + n * 16 + l15;
            f32x4 r = acc[m][n] + bias;
            *(f32x4*)(h + (size_t)node * HIDDEN + c0 + m * 16 + l4 * 4) = r;
        }
    }
}

// ===========================================================================
// Fused CSR aggregation + leaky-relu + energy tap + output cast.
// LAST=0: write split-bf16 (xhi,xlo) for next layer's GEMM.
// LAST=1: write f32 x to d_out.
// ===========================================================================
template <int LAST>
__global__ void agg_relu_tap(const float* __restrict__ h, const int* __restrict__ rowptr,
                             const int* __restrict__ es, const float* __restrict__ ew,
                             const float* __restrict__ We_l, const float* __restrict__ be_l,
                             const float* __restrict__ temp_l,
                             uint* __restrict__ xhi, uint* __restrict__ xlo,
                             float* __restrict__ xout, float* __restrict__ energy) {
    int gtid = blockIdx.x * blockDim.x + threadIdx.x;
    int n = gtid >> 6, lane = gtid & 63;
    if (n >= N_NODES) return;
    int j0 = rowptr[n], j1 = rowptr[n + 1];
    float2 acc = {0.f, 0.f};
    int j = j0;
    for (; j + 2 <= j1; j += 2) {
        int s0 = es[j], s1 = es[j + 1];
        float w0 = ew[j], w1 = ew[j + 1];
        float2 v0 = ((const float2*)(h + (size_t)s0 * HIDDEN))[lane];
        float2 v1 = ((const float2*)(h + (size_t)s1 * HIDDEN))[lane];
        acc.x += v0.x * w0 + v1.x * w1;
        acc.y += v0.y * w0 + v1.y * w1;
    }
    if (j < j1) {
        int s0 = es[j];
        float w0 = ew[j];
        float2 v0 = ((const float2*)(h + (size_t)s0 * HIDDEN))[lane];
        acc.x += v0.x * w0;
        acc.y += v0.y * w0;
    }
    acc.x = acc.x > 0.f ? acc.x : 0.01f * acc.x;
    acc.y = acc.y > 0.f ? acc.y : 0.01f * acc.y;

    if (LAST) {
        ((float2*)(xout + (size_t)n * HIDDEN))[lane] = acc;
    } else {
        ushort hx = f2bf(acc.x), hy = f2bf(acc.y);
        float hxf = __uint_as_float(((uint)hx) << 16);
        float hyf = __uint_as_float(((uint)hy) << 16);
        ushort lx = f2bf(acc.x - hxf), ly = f2bf(acc.y - hyf);
        xhi[(size_t)n * 64 + lane] = (uint)hx | ((uint)hy << 16);
        xlo[(size_t)n * 64 + lane] = (uint)lx | ((uint)ly << 16);
    }

    float2 we2 = ((const float2*)We_l)[lane];
    float dot = acc.x * we2.x + acc.y * we2.y;
    #pragma unroll
    for (int off = 32; off > 0; off >>= 1) dot += __shfl_xor(dot, off);
    if (lane == 0) energy[n] += (dot + be_l[0]) * temp_l[0];
}

extern "C" void kernel_launch(void* const* d_in, const int* in_sizes, int n_in,
                              void* d_out, int out_size, void* d_ws, size_t ws_size,
                              hipStream_t stream) {
    const float* x    = (const float*)d_in[0];
    const int*   src  = (const int*)d_in[1];
    const int*   dst  = (const int*)d_in[2];
    const float* w    = (const float*)d_in[3];
    const float* Ws   = (const float*)d_in[4];
    const float* bs   = (const float*)d_in[5];
    const float* We   = (const float*)d_in[6];
    const float* be   = (const float*)d_in[7];
    const float* temp = (const float*)d_in[8];

    float* energy = (float*)d_out;            // [N]
    float* xout   = (float*)d_out + N_NODES;  // [N,128] f32 final x
    // x hi/lo split scratch aliases the xout region (12.8M floats = 2x 6.4M uints)
    uint* xhi = (uint*)xout;
    uint* xlo = xhi + (size_t)N_NODES * 64;

    // workspace
    float*  h      = (float*)d_ws;                        // MPAD*128 f32
    int*    cnt    = (int*)(h + (size_t)MPAD * HIDDEN);
    int*    excl   = cnt + N_NODES;
    int*    bsums  = excl + N_NODES;                      // 128
    int*    rowptr = bsums + 128;                         // N+1
    int*    fillc  = rowptr + (N_NODES + 1);
    int*    es     = fillc + N_NODES;                     // E
    float*  ew     = (float*)(es + N_EDGES);              // E
    ushort* whi    = (ushort*)(ew + N_EDGES);             // 4*128*128
    ushort* wlo    = whi + N_LAYERS * HIDDEN * HIDDEN;

    // ---- CSR build ----
    hipMemsetAsync(cnt, 0, N_NODES * sizeof(int), stream);
    count_dst<<<(N_EDGES + 255) / 256, 256, 0, stream>>>(dst, cnt);
    int nblk = (N_NODES + 1023) / 1024;
    scan1<<<nblk, 256, 0, stream>>>(cnt, excl, bsums, N_NODES);
    scan2<<<1, 256, 0, stream>>>(bsums, nblk);
    scan3<<<(N_NODES + 1 + 255) / 256, 256, 0, stream>>>(excl, bsums, rowptr, N_NODES);
    hipMemsetAsync(fillc, 0, N_NODES * sizeof(int), stream);
    fill_csr<<<(N_EDGES + 255) / 256, 256, 0, stream>>>(src, dst, w, rowptr, fillc, es, ew);

    // ---- weight split prep ----
    prep_w<<<(N_LAYERS * HIDDEN * HIDDEN + 255) / 256, 256, 0, stream>>>(Ws, whi, wlo);

    // ---- tap0 + cast x0 ----
    tap0_cast<<<(N_NODES * 64) / 256, 256, 0, stream>>>(x, We, be, temp, energy, xhi, xlo);

    // ---- layers ----
    for (int i = 0; i < N_LAYERS; ++i) {
        gemm_mfma_split<<<(MPAD / 128), 256, 0, stream>>>(
            xhi, xlo, whi + (size_t)i * HIDDEN * HIDDEN, wlo + (size_t)i * HIDDEN * HIDDEN,
            bs + (size_t)i * HIDDEN, h);
        if (i < N_LAYERS - 1) {
            agg_relu_tap<0><<<(N_NODES * 64) / 256, 256, 0, stream>>>(
                h, rowptr, es, ew, We + (size_t)(i + 1) * HIDDEN, be + (i + 1),
                temp + (i + 1), xhi, xlo, xout, energy);
        } else {
            agg_relu_tap<1><<<(N_NODES * 64) / 256, 256, 0, stream>>>(
                h, rowptr, es, ew, We + (size_t)(i + 1) * HIDDEN, be + (i + 1),
                temp + (i + 1), xhi, xlo, xout, energy);
        }
    }
}

// Round 4
// 484.763 us; speedup vs baseline: 15.8376x; 1.1011x over previous
//
#include <hip/hip_runtime.h>
#include <hip/hip_bf16.h>

#define N_NODES 100000
#define N_EDGES 600000
#define HIDDEN 128
#define N_LAYERS 4
#define MPAD 100096   // N_NODES rounded up to 128

typedef short bf16x8 __attribute__((ext_vector_type(8)));
typedef float f32x4 __attribute__((ext_vector_type(4)));
typedef float f32x8 __attribute__((ext_vector_type(8)));

__device__ inline ushort f2bf(float f) {
    __hip_bfloat16 h = __float2bfloat16(f);
    return *reinterpret_cast<ushort*>(&h);
}

// ===========================================================================
// CSR build: count -> exclusive scan -> fill (src,w) in CSR-by-dst order
// ===========================================================================
__global__ void count_dst(const int* __restrict__ dst, int* __restrict__ cnt) {
    int e = blockIdx.x * blockDim.x + threadIdx.x;
    if (e >= N_EDGES) return;
    atomicAdd(&cnt[dst[e]], 1);
}

__global__ void scan1(const int* __restrict__ cnt, int* __restrict__ excl,
                      int* __restrict__ bsums, int n) {
    __shared__ int lds[8];
    int t = threadIdx.x;
    int base = blockIdx.x * 1024 + t * 4;
    int v0 = (base + 0 < n) ? cnt[base + 0] : 0;
    int v1 = (base + 1 < n) ? cnt[base + 1] : 0;
    int v2 = (base + 2 < n) ? cnt[base + 2] : 0;
    int v3 = (base + 3 < n) ? cnt[base + 3] : 0;
    int tsum = v0 + v1 + v2 + v3;
    int lane = t & 63, wv = t >> 6;
    int s = tsum;
    #pragma unroll
    for (int off = 1; off < 64; off <<= 1) {
        int u = __shfl_up(s, off);
        if (lane >= off) s += u;
    }
    if (lane == 63) lds[wv] = s;
    __syncthreads();
    if (t == 0) {
        int a = 0;
        #pragma unroll
        for (int i = 0; i < 4; ++i) { int bb = lds[i]; lds[i] = a; a += bb; }
        lds[4] = a;
    }
    __syncthreads();
    int excl_t = (s - tsum) + lds[wv];
    if (base + 0 < n) excl[base + 0] = excl_t;
    if (base + 1 < n) excl[base + 1] = excl_t + v0;
    if (base + 2 < n) excl[base + 2] = excl_t + v0 + v1;
    if (base + 3 < n) excl[base + 3] = excl_t + v0 + v1 + v2;
    if (t == 0) bsums[blockIdx.x] = lds[4];
}

__global__ void scan2(int* __restrict__ bsums, int nb) {
    __shared__ int wsum[4];
    int t = threadIdx.x;
    int v = (t < nb) ? bsums[t] : 0;
    int lane = t & 63, wv = t >> 6;
    int s = v;
    #pragma unroll
    for (int off = 1; off < 64; off <<= 1) {
        int u = __shfl_up(s, off);
        if (lane >= off) s += u;
    }
    if (lane == 63) wsum[wv] = s;
    __syncthreads();
    int add = 0;
    for (int i = 0; i < wv; ++i) add += wsum[i];
    if (t < nb) bsums[t] = (s - v) + add;
}

__global__ void scan3(const int* __restrict__ excl, const int* __restrict__ bsums,
                      int* __restrict__ rowptr, int n) {
    int i = blockIdx.x * blockDim.x + threadIdx.x;
    if (i < n) rowptr[i] = excl[i] + bsums[i >> 10];
    else if (i == n) rowptr[n] = N_EDGES;
}

__global__ void fill_csr(const int* __restrict__ src, const int* __restrict__ dst,
                         const float* __restrict__ w, const int* __restrict__ rowptr,
                         int* __restrict__ fillc, int* __restrict__ es,
                         float* __restrict__ ew) {
    int e = blockIdx.x * blockDim.x + threadIdx.x;
    if (e >= N_EDGES) return;
    int d = dst[e];
    int pos = atomicAdd(&fillc[d], 1);
    int slot = rowptr[d] + pos;
    es[slot] = src[e];
    ew[slot] = w[e];
}

// ===========================================================================
// Weight prep: whi/wlo[l][c][k] = split_bf16(Ws[l][k][c])  (transposed layout)
// ===========================================================================
__global__ void prep_w(const float* __restrict__ Ws, ushort* __restrict__ whi,
                       ushort* __restrict__ wlo) {
    int idx = blockIdx.x * blockDim.x + threadIdx.x;
    if (idx >= N_LAYERS * HIDDEN * HIDDEN) return;
    int l = idx >> 14;
    int r = idx & 16383;
    int c = r >> 7, k = r & 127;
    float v = Ws[(l << 14) + k * HIDDEN + c];
    ushort hi = f2bf(v);
    float hif = __uint_as_float(((uint)hi) << 16);
    ushort lo = f2bf(v - hif);
    whi[idx] = hi;
    wlo[idx] = lo;
}

// ===========================================================================
// GEMM via split-bf16 MFMA (hi*hi + hi*lo + lo*hi), swapped operands
// (A = W^T frag, B = x frag) so lane's D = h[node][c..c+3].
// Output h stored as bf16 (halves the gather payload downstream).
// TAP0=1: read f32 x directly, split in-register, and fuse the energy-0 tap
//         (wave 0 computes dot(x[n], We0) via 4-lane shfl reduce).
// ===========================================================================
template <int TAP0>
__global__ __launch_bounds__(256) void gemm_mfma_split(
    const uint* __restrict__ xhi, const uint* __restrict__ xlo,
    const float* __restrict__ xf,
    const ushort* __restrict__ whi, const ushort* __restrict__ wlo,
    const float* __restrict__ b, ushort* __restrict__ h,
    const float* __restrict__ We0, const float* __restrict__ be0,
    const float* __restrict__ temp0, float* __restrict__ energy) {
    int t = threadIdx.x;
    int lane = t & 63, wv = t >> 6;
    int l15 = lane & 15, l4 = lane >> 4;
    int row0 = blockIdx.x * 128;
    int c0 = wv * 32;

    // A fragments (W side), hoisted: [m][s]
    bf16x8 Ah[2][4], Al[2][4];
    #pragma unroll
    for (int m = 0; m < 2; ++m) {
        int c = c0 + m * 16 + l15;
        #pragma unroll
        for (int s = 0; s < 4; ++s) {
            int off = c * HIDDEN + s * 32 + l4 * 8;
            Ah[m][s] = *(const bf16x8*)(whi + off);
            Al[m][s] = *(const bf16x8*)(wlo + off);
        }
    }

    float be0v = 0.f, tp0v = 0.f;
    if (TAP0 && wv == 0) { be0v = be0[0]; tp0v = temp0[0]; }

    f32x4 acc[2][8];
    #pragma unroll
    for (int m = 0; m < 2; ++m)
        #pragma unroll
        for (int n = 0; n < 8; ++n)
            acc[m][n] = f32x4{0.f, 0.f, 0.f, 0.f};

    #pragma unroll
    for (int n = 0; n < 8; ++n) {
        int node = row0 + n * 16 + l15;
        int cnode = node < N_NODES ? node : N_NODES - 1;  // x arrays unpadded
        float dotn = 0.f;
        #pragma unroll
        for (int s = 0; s < 4; ++s) {
            bf16x8 bh, bl;
            if (TAP0) {
                f32x8 v = *(const f32x8*)(xf + (size_t)cnode * HIDDEN + s * 32 + l4 * 8);
                #pragma unroll
                for (int j = 0; j < 8; ++j) {
                    uint u = __float_as_uint(v[j]);
                    bh[j] = (short)(u >> 16);                     // truncated hi
                    float hif = __uint_as_float(u & 0xffff0000u);
                    bl[j] = (short)f2bf(v[j] - hif);              // RNE residual
                }
                if (wv == 0) {
                    f32x8 we = *(const f32x8*)(We0 + s * 32 + l4 * 8);
                    #pragma unroll
                    for (int j = 0; j < 8; ++j) dotn += v[j] * we[j];
                }
            } else {
                const ushort* xh = (const ushort*)xhi + (size_t)cnode * HIDDEN;
                const ushort* xl = (const ushort*)xlo + (size_t)cnode * HIDDEN;
                bh = *(const bf16x8*)(xh + s * 32 + l4 * 8);
                bl = *(const bf16x8*)(xl + s * 32 + l4 * 8);
            }
            #pragma unroll
            for (int m = 0; m < 2; ++m) {
                acc[m][n] = __builtin_amdgcn_mfma_f32_16x16x32_bf16(Ah[m][s], bh, acc[m][n], 0, 0, 0);
                acc[m][n] = __builtin_amdgcn_mfma_f32_16x16x32_bf16(Ah[m][s], bl, acc[m][n], 0, 0, 0);
                acc[m][n] = __builtin_amdgcn_mfma_f32_16x16x32_bf16(Al[m][s], bh, acc[m][n], 0, 0, 0);
            }
        }
        if (TAP0 && wv == 0) {
            dotn += __shfl_xor(dotn, 16);
            dotn += __shfl_xor(dotn, 32);
            if (lane < 16 && row0 + n * 16 + lane < N_NODES)
                energy[row0 + n * 16 + lane] = (dotn + be0v) * tp0v;
        }
    }

    // Epilogue: +bias, pack bf16, store (h padded to MPAD rows, unguarded)
    #pragma unroll
    for (int m = 0; m < 2; ++m) {
        f32x4 bias = *(const f32x4*)(b + c0 + m * 16 + l4 * 4);
        #pragma unroll
        for (int n = 0; n < 8; ++n) {
            int node = row0 + n * 16 + l15;
            f32x4 r = acc[m][n] + bias;
            uint2 packed;
            packed.x = (uint)f2bf(r[0]) | ((uint)f2bf(r[1]) << 16);
            packed.y = (uint)f2bf(r[2]) | ((uint)f2bf(r[3]) << 16);
            *(uint2*)(h + (size_t)node * HIDDEN + c0 + m * 16 + l4 * 4) = packed;
        }
    }
}

// ===========================================================================
// Fused CSR aggregation (bf16 gather) + leaky-relu + energy tap + output cast.
// LAST=0: write split-bf16 (xhi,xlo). LAST=1: write f32 x to d_out.
// ===========================================================================
template <int LAST>
__global__ void agg_relu_tap(const ushort* __restrict__ h, const int* __restrict__ rowptr,
                             const int* __restrict__ es, const float* __restrict__ ew,
                             const float* __restrict__ We_l, const float* __restrict__ be_l,
                             const float* __restrict__ temp_l,
                             uint* __restrict__ xhi, uint* __restrict__ xlo,
                             float* __restrict__ xout, float* __restrict__ energy) {
    int gtid = blockIdx.x * blockDim.x + threadIdx.x;
    int n = gtid >> 6, lane = gtid & 63;
    if (n >= N_NODES) return;
    int j0 = rowptr[n], j1 = rowptr[n + 1];
    float2 acc = {0.f, 0.f};
    int j = j0;
    for (; j + 2 <= j1; j += 2) {
        int s0 = es[j], s1 = es[j + 1];
        float w0 = ew[j], w1 = ew[j + 1];
        uint u0 = ((const uint*)(h + (size_t)s0 * HIDDEN))[lane];
        uint u1 = ((const uint*)(h + (size_t)s1 * HIDDEN))[lane];
        acc.x += __uint_as_float(u0 << 16) * w0 + __uint_as_float(u1 << 16) * w1;
        acc.y += __uint_as_float(u0 & 0xffff0000u) * w0 + __uint_as_float(u1 & 0xffff0000u) * w1;
    }
    if (j < j1) {
        int s0 = es[j];
        float w0 = ew[j];
        uint u0 = ((const uint*)(h + (size_t)s0 * HIDDEN))[lane];
        acc.x += __uint_as_float(u0 << 16) * w0;
        acc.y += __uint_as_float(u0 & 0xffff0000u) * w0;
    }
    acc.x = acc.x > 0.f ? acc.x : 0.01f * acc.x;
    acc.y = acc.y > 0.f ? acc.y : 0.01f * acc.y;

    if (LAST) {
        ((float2*)(xout + (size_t)n * HIDDEN))[lane] = acc;
    } else {
        ushort hx = f2bf(acc.x), hy = f2bf(acc.y);
        float hxf = __uint_as_float(((uint)hx) << 16);
        float hyf = __uint_as_float(((uint)hy) << 16);
        ushort lx = f2bf(acc.x - hxf), ly = f2bf(acc.y - hyf);
        xhi[(size_t)n * 64 + lane] = (uint)hx | ((uint)hy << 16);
        xlo[(size_t)n * 64 + lane] = (uint)lx | ((uint)ly << 16);
    }

    float2 we2 = ((const float2*)We_l)[lane];
    float dot = acc.x * we2.x + acc.y * we2.y;
    #pragma unroll
    for (int off = 32; off > 0; off >>= 1) dot += __shfl_xor(dot, off);
    if (lane == 0) energy[n] += (dot + be_l[0]) * temp_l[0];
}

extern "C" void kernel_launch(void* const* d_in, const int* in_sizes, int n_in,
                              void* d_out, int out_size, void* d_ws, size_t ws_size,
                              hipStream_t stream) {
    const float* x    = (const float*)d_in[0];
    const int*   src  = (const int*)d_in[1];
    const int*   dst  = (const int*)d_in[2];
    const float* w    = (const float*)d_in[3];
    const float* Ws   = (const float*)d_in[4];
    const float* bs   = (const float*)d_in[5];
    const float* We   = (const float*)d_in[6];
    const float* be   = (const float*)d_in[7];
    const float* temp = (const float*)d_in[8];

    float* energy = (float*)d_out;            // [N]
    float* xout   = (float*)d_out + N_NODES;  // [N,128] f32 final x
    uint* xhi = (uint*)xout;                  // split scratch aliases xout
    uint* xlo = xhi + (size_t)N_NODES * 64;

    // workspace
    ushort* h      = (ushort*)d_ws;                       // MPAD*128 bf16
    int*    cnt    = (int*)(h + (size_t)MPAD * HIDDEN);
    int*    excl   = cnt + N_NODES;
    int*    bsums  = excl + N_NODES;                      // 128
    int*    rowptr = bsums + 128;                         // N+1
    int*    fillc  = rowptr + (N_NODES + 1);
    int*    es     = fillc + N_NODES;                     // E
    float*  ew     = (float*)(es + N_EDGES);              // E
    ushort* whi    = (ushort*)(ew + N_EDGES);             // 4*128*128
    ushort* wlo    = whi + N_LAYERS * HIDDEN * HIDDEN;

    // ---- CSR build ----
    hipMemsetAsync(cnt, 0, N_NODES * sizeof(int), stream);
    count_dst<<<(N_EDGES + 255) / 256, 256, 0, stream>>>(dst, cnt);
    int nblk = (N_NODES + 1023) / 1024;
    scan1<<<nblk, 256, 0, stream>>>(cnt, excl, bsums, N_NODES);
    scan2<<<1, 256, 0, stream>>>(bsums, nblk);
    scan3<<<(N_NODES + 1 + 255) / 256, 256, 0, stream>>>(excl, bsums, rowptr, N_NODES);
    hipMemsetAsync(fillc, 0, N_NODES * sizeof(int), stream);
    fill_csr<<<(N_EDGES + 255) / 256, 256, 0, stream>>>(src, dst, w, rowptr, fillc, es, ew);

    // ---- weight split prep ----
    prep_w<<<(N_LAYERS * HIDDEN * HIDDEN + 255) / 256, 256, 0, stream>>>(Ws, whi, wlo);

    // ---- layers (layer 0 fuses tap0 + x cast) ----
    for (int i = 0; i < N_LAYERS; ++i) {
        if (i == 0) {
            gemm_mfma_split<1><<<(MPAD / 128), 256, 0, stream>>>(
                xhi, xlo, x, whi, wlo, bs, h, We, be, temp, energy);
        } else {
            gemm_mfma_split<0><<<(MPAD / 128), 256, 0, stream>>>(
                xhi, xlo, nullptr, whi + (size_t)i * HIDDEN * HIDDEN,
                wlo + (size_t)i * HIDDEN * HIDDEN, bs + (size_t)i * HIDDEN, h,
                nullptr, nullptr, nullptr, nullptr);
        }
        if (i < N_LAYERS - 1) {
            agg_relu_tap<0><<<(N_NODES * 64) / 256, 256, 0, stream>>>(
                h, rowptr, es, ew, We + (size_t)(i + 1) * HIDDEN, be + (i + 1),
                temp + (i + 1), xhi, xlo, xout, energy);
        } else {
            agg_relu_tap<1><<<(N_NODES * 64) / 256, 256, 0, stream>>>(
                h, rowptr, es, ew, We + (size_t)(i + 1) * HIDDEN, be + (i + 1),
                temp + (i + 1), xhi, xlo, xout, energy);
        }
    }
}

// Round 5
// 422.776 us; speedup vs baseline: 18.1596x; 1.1466x over previous
//
#include <hip/hip_runtime.h>
#include <hip/hip_bf16.h>

#define N_NODES 100000
#define N_EDGES 600000
#define HIDDEN 128
#define N_LAYERS 4
#define MPAD 100096   // N_NODES rounded up to 128 (and to 64)

typedef short bf16x8 __attribute__((ext_vector_type(8)));
typedef float f32x4 __attribute__((ext_vector_type(4)));

__device__ inline ushort f2bf(float f) {
    __hip_bfloat16 h = __float2bfloat16(f);
    return *reinterpret_cast<ushort*>(&h);
}

// ===========================================================================
// CSR build: count -> exclusive scan -> fill (src,w) packed int2, CSR-by-dst
// ===========================================================================
__global__ void count_dst(const int* __restrict__ dst, int* __restrict__ cnt) {
    int e = blockIdx.x * blockDim.x + threadIdx.x;
    if (e >= N_EDGES) return;
    atomicAdd(&cnt[dst[e]], 1);
}

__global__ void scan1(const int* __restrict__ cnt, int* __restrict__ excl,
                      int* __restrict__ bsums, int n) {
    __shared__ int lds[8];
    int t = threadIdx.x;
    int base = blockIdx.x * 1024 + t * 4;
    int v0 = (base + 0 < n) ? cnt[base + 0] : 0;
    int v1 = (base + 1 < n) ? cnt[base + 1] : 0;
    int v2 = (base + 2 < n) ? cnt[base + 2] : 0;
    int v3 = (base + 3 < n) ? cnt[base + 3] : 0;
    int tsum = v0 + v1 + v2 + v3;
    int lane = t & 63, wv = t >> 6;
    int s = tsum;
    #pragma unroll
    for (int off = 1; off < 64; off <<= 1) {
        int u = __shfl_up(s, off);
        if (lane >= off) s += u;
    }
    if (lane == 63) lds[wv] = s;
    __syncthreads();
    if (t == 0) {
        int a = 0;
        #pragma unroll
        for (int i = 0; i < 4; ++i) { int bb = lds[i]; lds[i] = a; a += bb; }
        lds[4] = a;
    }
    __syncthreads();
    int excl_t = (s - tsum) + lds[wv];
    if (base + 0 < n) excl[base + 0] = excl_t;
    if (base + 1 < n) excl[base + 1] = excl_t + v0;
    if (base + 2 < n) excl[base + 2] = excl_t + v0 + v1;
    if (base + 3 < n) excl[base + 3] = excl_t + v0 + v1 + v2;
    if (t == 0) bsums[blockIdx.x] = lds[4];
}

__global__ void scan2(int* __restrict__ bsums, int nb) {
    __shared__ int wsum[4];
    int t = threadIdx.x;
    int v = (t < nb) ? bsums[t] : 0;
    int lane = t & 63, wv = t >> 6;
    int s = v;
    #pragma unroll
    for (int off = 1; off < 64; off <<= 1) {
        int u = __shfl_up(s, off);
        if (lane >= off) s += u;
    }
    if (lane == 63) wsum[wv] = s;
    __syncthreads();
    int add = 0;
    for (int i = 0; i < wv; ++i) add += wsum[i];
    if (t < nb) bsums[t] = (s - v) + add;
}

__global__ void scan3(const int* __restrict__ excl, const int* __restrict__ bsums,
                      int* __restrict__ rowptr, int n) {
    int i = blockIdx.x * blockDim.x + threadIdx.x;
    if (i < n) rowptr[i] = excl[i] + bsums[i >> 10];
    else if (i == n) rowptr[n] = N_EDGES;
}

__global__ void fill_csr(const int* __restrict__ src, const int* __restrict__ dst,
                         const float* __restrict__ w, const int* __restrict__ rowptr,
                         int* __restrict__ fillc, int2* __restrict__ epack) {
    int e = blockIdx.x * blockDim.x + threadIdx.x;
    if (e >= N_EDGES) return;
    int d = dst[e];
    int pos = atomicAdd(&fillc[d], 1);
    int slot = rowptr[d] + pos;
    epack[slot] = make_int2(src[e], __float_as_int(w[e]));
}

// ===========================================================================
// Weight prep: whi/wlo[l][c][k] = split_bf16(Ws[l][k][c])  (transposed layout)
// ===========================================================================
__global__ void prep_w(const float* __restrict__ Ws, ushort* __restrict__ whi,
                       ushort* __restrict__ wlo) {
    int idx = blockIdx.x * blockDim.x + threadIdx.x;
    if (idx >= N_LAYERS * HIDDEN * HIDDEN) return;
    int l = idx >> 14;
    int r = idx & 16383;
    int c = r >> 7, k = r & 127;
    float v = Ws[(l << 14) + k * HIDDEN + c];
    ushort hi = f2bf(v);
    float hif = __uint_as_float(((uint)hi) << 16);
    ushort lo = f2bf(v - hif);
    whi[idx] = hi;
    wlo[idx] = lo;
}

// ===========================================================================
// tap0 + cast x0 -> (xhi, xlo) bf16 split. One wave per node.
// ===========================================================================
__global__ void tap0_cast(const float* __restrict__ x, const float* __restrict__ We_l,
                          const float* __restrict__ be_l, const float* __restrict__ temp_l,
                          float* __restrict__ energy, uint* __restrict__ xhi,
                          uint* __restrict__ xlo) {
    int gtid = blockIdx.x * blockDim.x + threadIdx.x;
    int n = gtid >> 6, lane = gtid & 63;
    if (n >= N_NODES) return;
    float2 v = ((const float2*)(x + (size_t)n * HIDDEN))[lane];
    ushort hx = f2bf(v.x), hy = f2bf(v.y);
    float hxf = __uint_as_float(((uint)hx) << 16);
    float hyf = __uint_as_float(((uint)hy) << 16);
    ushort lx = f2bf(v.x - hxf), ly = f2bf(v.y - hyf);
    xhi[(size_t)n * 64 + lane] = (uint)hx | ((uint)hy << 16);
    xlo[(size_t)n * 64 + lane] = (uint)lx | ((uint)ly << 16);
    float2 we2 = ((const float2*)We_l)[lane];
    float dot = v.x * we2.x + v.y * we2.y;
    #pragma unroll
    for (int off = 32; off > 0; off >>= 1) dot += __shfl_xor(dot, off);
    if (lane == 0) energy[n] = (dot + be_l[0]) * temp_l[0];
}

// ===========================================================================
// LDS-staged split-bf16 MFMA GEMM.
// Block: 256 thr / 4 waves; tile = 64 nodes x 128 cols; LDS = 32 KB
// (xhi tile 16 KB + xlo tile 16 KB), XOR-swizzled (col16B ^= (row&7)) so the
// stride-256B ds_read_b128 fragment reads are bank-conflict-free (2-way max).
// Wave w -> cols [w*32, w*32+32); 3 MFMA products hi*hi + hi*lo + lo*hi.
// Output h stored bf16, padded to MPAD rows.
// ===========================================================================
__global__ __launch_bounds__(256) void gemm_lds(
    const uint* __restrict__ xhi, const uint* __restrict__ xlo,
    const ushort* __restrict__ whi, const ushort* __restrict__ wlo,
    const float* __restrict__ b, ushort* __restrict__ h) {
    __shared__ uint4 sx4[2048];          // 32 KB
    char* sxb = (char*)sx4;
    int t = threadIdx.x;
    int lane = t & 63, wv = t >> 6;
    int l15 = lane & 15, l4 = lane >> 4;
    int row0 = blockIdx.x * 64;
    int c0 = wv * 32;

    // A fragments (W side), global (L1-hot), hoisted before staging
    bf16x8 Ah[2][4], Al[2][4];
    #pragma unroll
    for (int m = 0; m < 2; ++m) {
        int c = c0 + m * 16 + l15;
        #pragma unroll
        for (int s = 0; s < 4; ++s) {
            int off = c * HIDDEN + s * 32 + l4 * 8;
            Ah[m][s] = *(const bf16x8*)(whi + off);
            Al[m][s] = *(const bf16x8*)(wlo + off);
        }
    }

    // Stage x tile: per half, 1024 16B-chunks; thread t takes chunks j*256+t
    // (global reads fully coalesced), LDS write at swizzled column.
    const char* srcs[2] = {(const char*)xhi, (const char*)xlo};
    #pragma unroll
    for (int half = 0; half < 2; ++half) {
        #pragma unroll
        for (int j = 0; j < 4; ++j) {
            int c = j * 256 + t;          // chunk index in [0,1024)
            int row = c >> 4;             // 0..63
            int colb = (c & 15) * 16;     // byte col 0..255
            int grow = row0 + row;
            if (grow >= N_NODES) grow = N_NODES - 1;
            uint4 v = *(const uint4*)(srcs[half] + (size_t)grow * 256 + colb);
            int dst = half * 16384 + row * 256 + (colb ^ ((row & 7) << 4));
            *(uint4*)(sxb + dst) = v;
        }
    }
    __syncthreads();

    f32x4 acc[2][4];
    #pragma unroll
    for (int m = 0; m < 2; ++m)
        #pragma unroll
        for (int n = 0; n < 4; ++n)
            acc[m][n] = f32x4{0.f, 0.f, 0.f, 0.f};

    #pragma unroll
    for (int n = 0; n < 4; ++n) {
        int row = n * 16 + l15;
        int rsw = (row & 7) << 4;
        #pragma unroll
        for (int s = 0; s < 4; ++s) {
            int off = row * 256 + ((s * 64 + l4 * 16) ^ rsw);
            bf16x8 bh = *(const bf16x8*)(sxb + off);
            bf16x8 bl = *(const bf16x8*)(sxb + 16384 + off);
            #pragma unroll
            for (int m = 0; m < 2; ++m) {
                acc[m][n] = __builtin_amdgcn_mfma_f32_16x16x32_bf16(Ah[m][s], bh, acc[m][n], 0, 0, 0);
                acc[m][n] = __builtin_amdgcn_mfma_f32_16x16x32_bf16(Ah[m][s], bl, acc[m][n], 0, 0, 0);
                acc[m][n] = __builtin_amdgcn_mfma_f32_16x16x32_bf16(Al[m][s], bh, acc[m][n], 0, 0, 0);
            }
        }
    }

    // Epilogue: +bias, pack bf16, store (h padded to MPAD rows, unguarded)
    #pragma unroll
    for (int m = 0; m < 2; ++m) {
        f32x4 bias = *(const f32x4*)(b + c0 + m * 16 + l4 * 4);
        #pragma unroll
        for (int n = 0; n < 4; ++n) {
            int node = row0 + n * 16 + l15;
            f32x4 r = acc[m][n] + bias;
            uint2 packed;
            packed.x = (uint)f2bf(r[0]) | ((uint)f2bf(r[1]) << 16);
            packed.y = (uint)f2bf(r[2]) | ((uint)f2bf(r[3]) << 16);
            *(uint2*)(h + (size_t)node * HIDDEN + c0 + m * 16 + l4 * 4) = packed;
        }
    }
}

// ===========================================================================
// Fused CSR aggregation (bf16 gather, packed int2 edges) + leaky-relu +
// energy tap + output cast. LAST=0: write split-bf16. LAST=1: write f32 x.
// ===========================================================================
template <int LAST>
__global__ void agg_relu_tap(const ushort* __restrict__ h, const int* __restrict__ rowptr,
                             const int2* __restrict__ epack,
                             const float* __restrict__ We_l, const float* __restrict__ be_l,
                             const float* __restrict__ temp_l,
                             uint* __restrict__ xhi, uint* __restrict__ xlo,
                             float* __restrict__ xout, float* __restrict__ energy) {
    int gtid = blockIdx.x * blockDim.x + threadIdx.x;
    int n = gtid >> 6, lane = gtid & 63;
    if (n >= N_NODES) return;
    int j0 = rowptr[n], j1 = rowptr[n + 1];
    float2 acc = {0.f, 0.f};
    int j = j0;
    for (; j + 2 <= j1; j += 2) {
        int2 p0 = epack[j], p1 = epack[j + 1];
        float w0 = __int_as_float(p0.y), w1 = __int_as_float(p1.y);
        uint u0 = ((const uint*)(h + (size_t)p0.x * HIDDEN))[lane];
        uint u1 = ((const uint*)(h + (size_t)p1.x * HIDDEN))[lane];
        acc.x += __uint_as_float(u0 << 16) * w0 + __uint_as_float(u1 << 16) * w1;
        acc.y += __uint_as_float(u0 & 0xffff0000u) * w0 + __uint_as_float(u1 & 0xffff0000u) * w1;
    }
    if (j < j1) {
        int2 p0 = epack[j];
        float w0 = __int_as_float(p0.y);
        uint u0 = ((const uint*)(h + (size_t)p0.x * HIDDEN))[lane];
        acc.x += __uint_as_float(u0 << 16) * w0;
        acc.y += __uint_as_float(u0 & 0xffff0000u) * w0;
    }
    acc.x = acc.x > 0.f ? acc.x : 0.01f * acc.x;
    acc.y = acc.y > 0.f ? acc.y : 0.01f * acc.y;

    if (LAST) {
        ((float2*)(xout + (size_t)n * HIDDEN))[lane] = acc;
    } else {
        ushort hx = f2bf(acc.x), hy = f2bf(acc.y);
        float hxf = __uint_as_float(((uint)hx) << 16);
        float hyf = __uint_as_float(((uint)hy) << 16);
        ushort lx = f2bf(acc.x - hxf), ly = f2bf(acc.y - hyf);
        xhi[(size_t)n * 64 + lane] = (uint)hx | ((uint)hy << 16);
        xlo[(size_t)n * 64 + lane] = (uint)lx | ((uint)ly << 16);
    }

    float2 we2 = ((const float2*)We_l)[lane];
    float dot = acc.x * we2.x + acc.y * we2.y;
    #pragma unroll
    for (int off = 32; off > 0; off >>= 1) dot += __shfl_xor(dot, off);
    if (lane == 0) energy[n] += (dot + be_l[0]) * temp_l[0];
}

extern "C" void kernel_launch(void* const* d_in, const int* in_sizes, int n_in,
                              void* d_out, int out_size, void* d_ws, size_t ws_size,
                              hipStream_t stream) {
    const float* x    = (const float*)d_in[0];
    const int*   src  = (const int*)d_in[1];
    const int*   dst  = (const int*)d_in[2];
    const float* w    = (const float*)d_in[3];
    const float* Ws   = (const float*)d_in[4];
    const float* bs   = (const float*)d_in[5];
    const float* We   = (const float*)d_in[6];
    const float* be   = (const float*)d_in[7];
    const float* temp = (const float*)d_in[8];

    float* energy = (float*)d_out;            // [N]
    float* xout   = (float*)d_out + N_NODES;  // [N,128] f32 final x
    uint* xhi = (uint*)xout;                  // split scratch aliases xout
    uint* xlo = xhi + (size_t)N_NODES * 64;

    // workspace
    ushort* h      = (ushort*)d_ws;                       // MPAD*128 bf16
    int*    cnt    = (int*)(h + (size_t)MPAD * HIDDEN);
    int*    excl   = cnt + N_NODES;
    int*    bsums  = excl + N_NODES;                      // 128
    int*    rowptr = bsums + 128;                         // N+1
    int*    fillc  = rowptr + (N_NODES + 1);
    int2*   epack  = (int2*)(fillc + N_NODES);            // E (8B each)
    ushort* whi    = (ushort*)(epack + N_EDGES);          // 4*128*128
    ushort* wlo    = whi + N_LAYERS * HIDDEN * HIDDEN;

    // ---- CSR build ----
    hipMemsetAsync(cnt, 0, N_NODES * sizeof(int), stream);
    count_dst<<<(N_EDGES + 255) / 256, 256, 0, stream>>>(dst, cnt);
    int nblk = (N_NODES + 1023) / 1024;
    scan1<<<nblk, 256, 0, stream>>>(cnt, excl, bsums, N_NODES);
    scan2<<<1, 256, 0, stream>>>(bsums, nblk);
    scan3<<<(N_NODES + 1 + 255) / 256, 256, 0, stream>>>(excl, bsums, rowptr, N_NODES);
    hipMemsetAsync(fillc, 0, N_NODES * sizeof(int), stream);
    fill_csr<<<(N_EDGES + 255) / 256, 256, 0, stream>>>(src, dst, w, rowptr, fillc, epack);

    // ---- weight split prep ----
    prep_w<<<(N_LAYERS * HIDDEN * HIDDEN + 255) / 256, 256, 0, stream>>>(Ws, whi, wlo);

    // ---- tap0 + cast x0 ----
    tap0_cast<<<(N_NODES * 64) / 256, 256, 0, stream>>>(x, We, be, temp, energy, xhi, xlo);

    // ---- layers ----
    for (int i = 0; i < N_LAYERS; ++i) {
        gemm_lds<<<(MPAD / 64), 256, 0, stream>>>(
            xhi, xlo, whi + (size_t)i * HIDDEN * HIDDEN,
            wlo + (size_t)i * HIDDEN * HIDDEN, bs + (size_t)i * HIDDEN, h);
        if (i < N_LAYERS - 1) {
            agg_relu_tap<0><<<(N_NODES * 64) / 256, 256, 0, stream>>>(
                h, rowptr, epack, We + (size_t)(i + 1) * HIDDEN, be + (i + 1),
                temp + (i + 1), xhi, xlo, xout, energy);
        } else {
            agg_relu_tap<1><<<(N_NODES * 64) / 256, 256, 0, stream>>>(
                h, rowptr, epack, We + (size_t)(i + 1) * HIDDEN, be + (i + 1),
                temp + (i + 1), xhi, xlo, xout, energy);
        }
    }
}

// Round 6
// 380.817 us; speedup vs baseline: 20.1605x; 1.1102x over previous
//
#include <hip/hip_runtime.h>
#include <hip/hip_bf16.h>

#define N_NODES 100000
#define N_EDGES 600000
#define HIDDEN 128
#define N_LAYERS 4
#define MPAD 100096   // N_NODES rounded up to 128 (and to 64)

typedef short bf16x8 __attribute__((ext_vector_type(8)));
typedef float f32x4 __attribute__((ext_vector_type(4)));

__device__ inline ushort f2bf(float f) {
    __hip_bfloat16 h = __float2bfloat16(f);
    return *reinterpret_cast<ushort*>(&h);
}

// ===========================================================================
// CSR build: count -> exclusive scan -> fill (src,w) packed int2, CSR-by-dst
// ===========================================================================
__global__ void count_dst(const int* __restrict__ dst, int* __restrict__ cnt) {
    int e = blockIdx.x * blockDim.x + threadIdx.x;
    if (e >= N_EDGES) return;
    atomicAdd(&cnt[dst[e]], 1);
}

__global__ void scan1(const int* __restrict__ cnt, int* __restrict__ excl,
                      int* __restrict__ bsums, int n) {
    __shared__ int lds[8];
    int t = threadIdx.x;
    int base = blockIdx.x * 1024 + t * 4;
    int v0 = (base + 0 < n) ? cnt[base + 0] : 0;
    int v1 = (base + 1 < n) ? cnt[base + 1] : 0;
    int v2 = (base + 2 < n) ? cnt[base + 2] : 0;
    int v3 = (base + 3 < n) ? cnt[base + 3] : 0;
    int tsum = v0 + v1 + v2 + v3;
    int lane = t & 63, wv = t >> 6;
    int s = tsum;
    #pragma unroll
    for (int off = 1; off < 64; off <<= 1) {
        int u = __shfl_up(s, off);
        if (lane >= off) s += u;
    }
    if (lane == 63) lds[wv] = s;
    __syncthreads();
    if (t == 0) {
        int a = 0;
        #pragma unroll
        for (int i = 0; i < 4; ++i) { int bb = lds[i]; lds[i] = a; a += bb; }
        lds[4] = a;
    }
    __syncthreads();
    int excl_t = (s - tsum) + lds[wv];
    if (base + 0 < n) excl[base + 0] = excl_t;
    if (base + 1 < n) excl[base + 1] = excl_t + v0;
    if (base + 2 < n) excl[base + 2] = excl_t + v0 + v1;
    if (base + 3 < n) excl[base + 3] = excl_t + v0 + v1 + v2;
    if (t == 0) bsums[blockIdx.x] = lds[4];
}

__global__ void scan2(int* __restrict__ bsums, int nb) {
    __shared__ int wsum[4];
    int t = threadIdx.x;
    int v = (t < nb) ? bsums[t] : 0;
    int lane = t & 63, wv = t >> 6;
    int s = v;
    #pragma unroll
    for (int off = 1; off < 64; off <<= 1) {
        int u = __shfl_up(s, off);
        if (lane >= off) s += u;
    }
    if (lane == 63) wsum[wv] = s;
    __syncthreads();
    int add = 0;
    for (int i = 0; i < wv; ++i) add += wsum[i];
    if (t < nb) bsums[t] = (s - v) + add;
}

__global__ void scan3(const int* __restrict__ excl, const int* __restrict__ bsums,
                      int* __restrict__ rowptr, int n) {
    int i = blockIdx.x * blockDim.x + threadIdx.x;
    if (i < n) rowptr[i] = excl[i] + bsums[i >> 10];
    else if (i == n) rowptr[n] = N_EDGES;
}

__global__ void fill_csr(const int* __restrict__ src, const int* __restrict__ dst,
                         const float* __restrict__ w, const int* __restrict__ rowptr,
                         int* __restrict__ fillc, int2* __restrict__ epack) {
    int e = blockIdx.x * blockDim.x + threadIdx.x;
    if (e >= N_EDGES) return;
    int d = dst[e];
    int pos = atomicAdd(&fillc[d], 1);
    int slot = rowptr[d] + pos;
    epack[slot] = make_int2(src[e], __float_as_int(w[e]));
}

// ===========================================================================
// Weight prep: whi/wlo[l][c][k] = split_bf16(Ws[l][k][c])  (transposed layout)
// ===========================================================================
__global__ void prep_w(const float* __restrict__ Ws, ushort* __restrict__ whi,
                       ushort* __restrict__ wlo) {
    int idx = blockIdx.x * blockDim.x + threadIdx.x;
    if (idx >= N_LAYERS * HIDDEN * HIDDEN) return;
    int l = idx >> 14;
    int r = idx & 16383;
    int c = r >> 7, k = r & 127;
    float v = Ws[(l << 14) + k * HIDDEN + c];
    ushort hi = f2bf(v);
    float hif = __uint_as_float(((uint)hi) << 16);
    ushort lo = f2bf(v - hif);
    whi[idx] = hi;
    wlo[idx] = lo;
}

// ===========================================================================
// tap0 + cast x0 -> bf16. One wave per node.
// ===========================================================================
__global__ void tap0_cast(const float* __restrict__ x, const float* __restrict__ We_l,
                          const float* __restrict__ be_l, const float* __restrict__ temp_l,
                          float* __restrict__ energy, uint* __restrict__ xb) {
    int gtid = blockIdx.x * blockDim.x + threadIdx.x;
    int n = gtid >> 6, lane = gtid & 63;
    if (n >= N_NODES) return;
    float2 v = ((const float2*)(x + (size_t)n * HIDDEN))[lane];
    xb[(size_t)n * 64 + lane] = (uint)f2bf(v.x) | ((uint)f2bf(v.y) << 16);
    float2 we2 = ((const float2*)We_l)[lane];
    float dot = v.x * we2.x + v.y * we2.y;
    #pragma unroll
    for (int off = 32; off > 0; off >>= 1) dot += __shfl_xor(dot, off);
    if (lane == 0) energy[n] = (dot + be_l[0]) * temp_l[0];
}

// ===========================================================================
// LDS-staged MFMA GEMM: x plain bf16, W split (2 products Whi*x + Wlo*x).
// Block: 256 thr / 4 waves; tile = 64 nodes x 128 cols; LDS = 16 KB,
// XOR-swizzled (col16B ^= (row&7)) so stride-256B ds_read_b128 is
// conflict-free. Wave w -> cols [w*32, w*32+32). h out bf16, MPAD rows.
// ===========================================================================
__global__ __launch_bounds__(256) void gemm_lds(
    const uint* __restrict__ xb,
    const ushort* __restrict__ whi, const ushort* __restrict__ wlo,
    const float* __restrict__ b, ushort* __restrict__ h) {
    __shared__ uint4 sx4[1024];          // 16 KB
    char* sxb = (char*)sx4;
    int t = threadIdx.x;
    int lane = t & 63, wv = t >> 6;
    int l15 = lane & 15, l4 = lane >> 4;
    int row0 = blockIdx.x * 64;
    int c0 = wv * 32;

    // A fragments (W side), global (L1-hot), hoisted before staging
    bf16x8 Ah[2][4], Al[2][4];
    #pragma unroll
    for (int m = 0; m < 2; ++m) {
        int c = c0 + m * 16 + l15;
        #pragma unroll
        for (int s = 0; s < 4; ++s) {
            int off = c * HIDDEN + s * 32 + l4 * 8;
            Ah[m][s] = *(const bf16x8*)(whi + off);
            Al[m][s] = *(const bf16x8*)(wlo + off);
        }
    }

    // Stage x tile: 1024 16B-chunks; thread t takes chunks j*256+t
    // (coalesced global reads), LDS write at swizzled column.
    #pragma unroll
    for (int j = 0; j < 4; ++j) {
        int c = j * 256 + t;          // chunk index in [0,1024)
        int row = c >> 4;             // 0..63
        int colb = (c & 15) * 16;     // byte col 0..255
        int grow = row0 + row;
        if (grow >= N_NODES) grow = N_NODES - 1;
        uint4 v = *(const uint4*)((const char*)xb + (size_t)grow * 256 + colb);
        *(uint4*)(sxb + row * 256 + (colb ^ ((row & 7) << 4))) = v;
    }
    __syncthreads();

    f32x4 acc[2][4];
    #pragma unroll
    for (int m = 0; m < 2; ++m)
        #pragma unroll
        for (int n = 0; n < 4; ++n)
            acc[m][n] = f32x4{0.f, 0.f, 0.f, 0.f};

    #pragma unroll
    for (int n = 0; n < 4; ++n) {
        int row = n * 16 + l15;
        int rsw = (row & 7) << 4;
        #pragma unroll
        for (int s = 0; s < 4; ++s) {
            bf16x8 bh = *(const bf16x8*)(sxb + row * 256 + ((s * 64 + l4 * 16) ^ rsw));
            #pragma unroll
            for (int m = 0; m < 2; ++m) {
                acc[m][n] = __builtin_amdgcn_mfma_f32_16x16x32_bf16(Ah[m][s], bh, acc[m][n], 0, 0, 0);
                acc[m][n] = __builtin_amdgcn_mfma_f32_16x16x32_bf16(Al[m][s], bh, acc[m][n], 0, 0, 0);
            }
        }
    }

    // Epilogue: +bias, pack bf16, store (h padded to MPAD rows, unguarded)
    #pragma unroll
    for (int m = 0; m < 2; ++m) {
        f32x4 bias = *(const f32x4*)(b + c0 + m * 16 + l4 * 4);
        #pragma unroll
        for (int n = 0; n < 4; ++n) {
            int node = row0 + n * 16 + l15;
            f32x4 r = acc[m][n] + bias;
            uint2 packed;
            packed.x = (uint)f2bf(r[0]) | ((uint)f2bf(r[1]) << 16);
            packed.y = (uint)f2bf(r[2]) | ((uint)f2bf(r[3]) << 16);
            *(uint2*)(h + (size_t)node * HIDDEN + c0 + m * 16 + l4 * 4) = packed;
        }
    }
}

// ===========================================================================
// Fused CSR aggregation (bf16 gather, 4-deep MLP) + leaky-relu + energy tap.
// LAST=0: write bf16 x for next GEMM. LAST=1: write f32 x to d_out.
// ===========================================================================
template <int LAST>
__global__ void agg_relu_tap(const ushort* __restrict__ h, const int* __restrict__ rowptr,
                             const int2* __restrict__ epack,
                             const float* __restrict__ We_l, const float* __restrict__ be_l,
                             const float* __restrict__ temp_l,
                             uint* __restrict__ xb, float* __restrict__ xout,
                             float* __restrict__ energy) {
    int gtid = blockIdx.x * blockDim.x + threadIdx.x;
    int n = gtid >> 6, lane = gtid & 63;
    if (n >= N_NODES) return;
    int j0 = rowptr[n], j1 = rowptr[n + 1];
    float2 acc = {0.f, 0.f};
    int j = j0;
    // 4-wide: 4 independent gathers in flight
    for (; j + 4 <= j1; j += 4) {
        int2 p0 = epack[j], p1 = epack[j + 1], p2 = epack[j + 2], p3 = epack[j + 3];
        uint u0 = ((const uint*)(h + (size_t)p0.x * HIDDEN))[lane];
        uint u1 = ((const uint*)(h + (size_t)p1.x * HIDDEN))[lane];
        uint u2 = ((const uint*)(h + (size_t)p2.x * HIDDEN))[lane];
        uint u3 = ((const uint*)(h + (size_t)p3.x * HIDDEN))[lane];
        float w0 = __int_as_float(p0.y), w1 = __int_as_float(p1.y);
        float w2 = __int_as_float(p2.y), w3 = __int_as_float(p3.y);
        acc.x += __uint_as_float(u0 << 16) * w0 + __uint_as_float(u1 << 16) * w1
               + __uint_as_float(u2 << 16) * w2 + __uint_as_float(u3 << 16) * w3;
        acc.y += __uint_as_float(u0 & 0xffff0000u) * w0 + __uint_as_float(u1 & 0xffff0000u) * w1
               + __uint_as_float(u2 & 0xffff0000u) * w2 + __uint_as_float(u3 & 0xffff0000u) * w3;
    }
    for (; j + 2 <= j1; j += 2) {
        int2 p0 = epack[j], p1 = epack[j + 1];
        uint u0 = ((const uint*)(h + (size_t)p0.x * HIDDEN))[lane];
        uint u1 = ((const uint*)(h + (size_t)p1.x * HIDDEN))[lane];
        float w0 = __int_as_float(p0.y), w1 = __int_as_float(p1.y);
        acc.x += __uint_as_float(u0 << 16) * w0 + __uint_as_float(u1 << 16) * w1;
        acc.y += __uint_as_float(u0 & 0xffff0000u) * w0 + __uint_as_float(u1 & 0xffff0000u) * w1;
    }
    if (j < j1) {
        int2 p0 = epack[j];
        float w0 = __int_as_float(p0.y);
        uint u0 = ((const uint*)(h + (size_t)p0.x * HIDDEN))[lane];
        acc.x += __uint_as_float(u0 << 16) * w0;
        acc.y += __uint_as_float(u0 & 0xffff0000u) * w0;
    }
    acc.x = acc.x > 0.f ? acc.x : 0.01f * acc.x;
    acc.y = acc.y > 0.f ? acc.y : 0.01f * acc.y;

    if (LAST) {
        ((float2*)(xout + (size_t)n * HIDDEN))[lane] = acc;
    } else {
        xb[(size_t)n * 64 + lane] = (uint)f2bf(acc.x) | ((uint)f2bf(acc.y) << 16);
    }

    float2 we2 = ((const float2*)We_l)[lane];
    float dot = acc.x * we2.x + acc.y * we2.y;
    #pragma unroll
    for (int off = 32; off > 0; off >>= 1) dot += __shfl_xor(dot, off);
    if (lane == 0) energy[n] += (dot + be_l[0]) * temp_l[0];
}

extern "C" void kernel_launch(void* const* d_in, const int* in_sizes, int n_in,
                              void* d_out, int out_size, void* d_ws, size_t ws_size,
                              hipStream_t stream) {
    const float* x    = (const float*)d_in[0];
    const int*   src  = (const int*)d_in[1];
    const int*   dst  = (const int*)d_in[2];
    const float* w    = (const float*)d_in[3];
    const float* Ws   = (const float*)d_in[4];
    const float* bs   = (const float*)d_in[5];
    const float* We   = (const float*)d_in[6];
    const float* be   = (const float*)d_in[7];
    const float* temp = (const float*)d_in[8];

    float* energy = (float*)d_out;            // [N]
    float* xout   = (float*)d_out + N_NODES;  // [N,128] f32 final x
    uint* xb = (uint*)xout;                   // bf16 x scratch aliases xout

    // workspace
    ushort* h      = (ushort*)d_ws;                       // MPAD*128 bf16
    int*    cnt    = (int*)(h + (size_t)MPAD * HIDDEN);
    int*    excl   = cnt + N_NODES;
    int*    bsums  = excl + N_NODES;                      // 128
    int*    rowptr = bsums + 128;                         // N+1
    int*    fillc  = rowptr + (N_NODES + 1);
    int2*   epack  = (int2*)(fillc + N_NODES);            // E (8B each)
    ushort* whi    = (ushort*)(epack + N_EDGES);          // 4*128*128
    ushort* wlo    = whi + N_LAYERS * HIDDEN * HIDDEN;

    // ---- CSR build ----
    hipMemsetAsync(cnt, 0, N_NODES * sizeof(int), stream);
    count_dst<<<(N_EDGES + 255) / 256, 256, 0, stream>>>(dst, cnt);
    int nblk = (N_NODES + 1023) / 1024;
    scan1<<<nblk, 256, 0, stream>>>(cnt, excl, bsums, N_NODES);
    scan2<<<1, 256, 0, stream>>>(bsums, nblk);
    scan3<<<(N_NODES + 1 + 255) / 256, 256, 0, stream>>>(excl, bsums, rowptr, N_NODES);
    hipMemsetAsync(fillc, 0, N_NODES * sizeof(int), stream);
    fill_csr<<<(N_EDGES + 255) / 256, 256, 0, stream>>>(src, dst, w, rowptr, fillc, epack);

    // ---- weight split prep ----
    prep_w<<<(N_LAYERS * HIDDEN * HIDDEN + 255) / 256, 256, 0, stream>>>(Ws, whi, wlo);

    // ---- tap0 + cast x0 ----
    tap0_cast<<<(N_NODES * 64) / 256, 256, 0, stream>>>(x, We, be, temp, energy, xb);

    // ---- layers ----
    for (int i = 0; i < N_LAYERS; ++i) {
        gemm_lds<<<(MPAD / 64), 256, 0, stream>>>(
            xb, whi + (size_t)i * HIDDEN * HIDDEN,
            wlo + (size_t)i * HIDDEN * HIDDEN, bs + (size_t)i * HIDDEN, h);
        if (i < N_LAYERS - 1) {
            agg_relu_tap<0><<<(N_NODES * 64) / 256, 256, 0, stream>>>(
                h, rowptr, epack, We + (size_t)(i + 1) * HIDDEN, be + (i + 1),
                temp + (i + 1), xb, xout, energy);
        } else {
            agg_relu_tap<1><<<(N_NODES * 64) / 256, 256, 0, stream>>>(
                h, rowptr, epack, We + (size_t)(i + 1) * HIDDEN, be + (i + 1),
                temp + (i + 1), xb, xout, energy);
        }
    }
}

// Round 7
// 375.831 us; speedup vs baseline: 20.4280x; 1.0133x over previous
//
#include <hip/hip_runtime.h>
#include <hip/hip_bf16.h>

#define N_NODES 100000
#define N_EDGES 600000
#define HIDDEN 128
#define N_LAYERS 4
#define MPAD 100096   // N_NODES rounded up to 128 (and to 64)

#define TAP0_BLOCKS ((N_NODES * 64) / 256)                       // 25000
#define CNT_BLOCKS ((N_EDGES + 255) / 256)                       // 2344
#define PREPW_BLOCKS ((N_LAYERS * HIDDEN * HIDDEN + 255) / 256)  // 256

typedef short bf16x8 __attribute__((ext_vector_type(8)));
typedef float f32x4 __attribute__((ext_vector_type(4)));

__device__ inline ushort f2bf(float f) {
    __hip_bfloat16 h = __float2bfloat16(f);
    return *reinterpret_cast<ushort*>(&h);
}

// ===========================================================================
// Prologue (fused independent prep): tap0+cast x0 | count_dst | prep_w
// ===========================================================================
__global__ void prologue(const float* __restrict__ x, const float* __restrict__ We,
                         const float* __restrict__ be, const float* __restrict__ temp,
                         float* __restrict__ energy, uint* __restrict__ xb,
                         const int* __restrict__ dst, int* __restrict__ cnt,
                         const float* __restrict__ Ws, ushort* __restrict__ whi,
                         ushort* __restrict__ wlo) {
    int b = blockIdx.x;
    if (b < TAP0_BLOCKS) {
        // --- tap0 + cast x0 -> bf16 (one wave per node) ---
        int gtid = b * 256 + threadIdx.x;
        int n = gtid >> 6, lane = gtid & 63;
        float2 v = ((const float2*)(x + (size_t)n * HIDDEN))[lane];
        xb[(size_t)n * 64 + lane] = (uint)f2bf(v.x) | ((uint)f2bf(v.y) << 16);
        float2 we2 = ((const float2*)We)[lane];
        float dot = v.x * we2.x + v.y * we2.y;
        #pragma unroll
        for (int off = 32; off > 0; off >>= 1) dot += __shfl_xor(dot, off);
        if (lane == 0) energy[n] = (dot + be[0]) * temp[0];
    } else if (b < TAP0_BLOCKS + CNT_BLOCKS) {
        // --- count dst degree ---
        int e = (b - TAP0_BLOCKS) * 256 + threadIdx.x;
        if (e < N_EDGES) atomicAdd(&cnt[dst[e]], 1);
    } else {
        // --- weight split: whi/wlo[l][c][k] = split_bf16(Ws[l][k][c]) ---
        int idx = (b - TAP0_BLOCKS - CNT_BLOCKS) * 256 + threadIdx.x;
        if (idx < N_LAYERS * HIDDEN * HIDDEN) {
            int l = idx >> 14;
            int r = idx & 16383;
            int c = r >> 7, k = r & 127;
            float v = Ws[(l << 14) + k * HIDDEN + c];
            ushort hi = f2bf(v);
            float hif = __uint_as_float(((uint)hi) << 16);
            whi[idx] = hi;
            wlo[idx] = f2bf(v - hif);
        }
    }
}

// ===========================================================================
// Exclusive scan (3 passes) over cnt -> rowptr
// ===========================================================================
__global__ void scan1(const int* __restrict__ cnt, int* __restrict__ excl,
                      int* __restrict__ bsums, int n) {
    __shared__ int lds[8];
    int t = threadIdx.x;
    int base = blockIdx.x * 1024 + t * 4;
    int v0 = (base + 0 < n) ? cnt[base + 0] : 0;
    int v1 = (base + 1 < n) ? cnt[base + 1] : 0;
    int v2 = (base + 2 < n) ? cnt[base + 2] : 0;
    int v3 = (base + 3 < n) ? cnt[base + 3] : 0;
    int tsum = v0 + v1 + v2 + v3;
    int lane = t & 63, wv = t >> 6;
    int s = tsum;
    #pragma unroll
    for (int off = 1; off < 64; off <<= 1) {
        int u = __shfl_up(s, off);
        if (lane >= off) s += u;
    }
    if (lane == 63) lds[wv] = s;
    __syncthreads();
    if (t == 0) {
        int a = 0;
        #pragma unroll
        for (int i = 0; i < 4; ++i) { int bb = lds[i]; lds[i] = a; a += bb; }
        lds[4] = a;
    }
    __syncthreads();
    int excl_t = (s - tsum) + lds[wv];
    if (base + 0 < n) excl[base + 0] = excl_t;
    if (base + 1 < n) excl[base + 1] = excl_t + v0;
    if (base + 2 < n) excl[base + 2] = excl_t + v0 + v1;
    if (base + 3 < n) excl[base + 3] = excl_t + v0 + v1 + v2;
    if (t == 0) bsums[blockIdx.x] = lds[4];
}

__global__ void scan2(int* __restrict__ bsums, int nb) {
    __shared__ int wsum[4];
    int t = threadIdx.x;
    int v = (t < nb) ? bsums[t] : 0;
    int lane = t & 63, wv = t >> 6;
    int s = v;
    #pragma unroll
    for (int off = 1; off < 64; off <<= 1) {
        int u = __shfl_up(s, off);
        if (lane >= off) s += u;
    }
    if (lane == 63) wsum[wv] = s;
    __syncthreads();
    int add = 0;
    for (int i = 0; i < wv; ++i) add += wsum[i];
    if (t < nb) bsums[t] = (s - v) + add;
}

__global__ void scan3(const int* __restrict__ excl, const int* __restrict__ bsums,
                      int* __restrict__ rowptr, int n) {
    int i = blockIdx.x * blockDim.x + threadIdx.x;
    if (i < n) rowptr[i] = excl[i] + bsums[i >> 10];
    else if (i == n) rowptr[n] = N_EDGES;
}

__global__ void fill_csr(const int* __restrict__ src, const int* __restrict__ dst,
                         const float* __restrict__ w, const int* __restrict__ rowptr,
                         int* __restrict__ fillc, int2* __restrict__ epack) {
    int e = blockIdx.x * blockDim.x + threadIdx.x;
    if (e >= N_EDGES) return;
    int d = dst[e];
    int pos = atomicAdd(&fillc[d], 1);
    int slot = rowptr[d] + pos;
    epack[slot] = make_int2(src[e], __float_as_int(w[e]));
}

// ===========================================================================
// LDS-staged MFMA GEMM: x plain bf16, W split (2 products Whi*x + Wlo*x).
// Block: 256 thr / 4 waves; tile = 64 nodes x 128 cols; LDS 16 KB,
// XOR-swizzled (col16B ^= (row&7)) -> conflict-free ds_read_b128.
// ===========================================================================
__global__ __launch_bounds__(256) void gemm_lds(
    const uint* __restrict__ xb,
    const ushort* __restrict__ whi, const ushort* __restrict__ wlo,
    const float* __restrict__ b, ushort* __restrict__ h) {
    __shared__ uint4 sx4[1024];          // 16 KB
    char* sxb = (char*)sx4;
    int t = threadIdx.x;
    int lane = t & 63, wv = t >> 6;
    int l15 = lane & 15, l4 = lane >> 4;
    int row0 = blockIdx.x * 64;
    int c0 = wv * 32;

    // A fragments (W side), global (L1-hot), hoisted before staging
    bf16x8 Ah[2][4], Al[2][4];
    #pragma unroll
    for (int m = 0; m < 2; ++m) {
        int c = c0 + m * 16 + l15;
        #pragma unroll
        for (int s = 0; s < 4; ++s) {
            int off = c * HIDDEN + s * 32 + l4 * 8;
            Ah[m][s] = *(const bf16x8*)(whi + off);
            Al[m][s] = *(const bf16x8*)(wlo + off);
        }
    }

    // Stage x tile: 1024 16B-chunks; thread t takes chunks j*256+t
    #pragma unroll
    for (int j = 0; j < 4; ++j) {
        int c = j * 256 + t;          // chunk index in [0,1024)
        int row = c >> 4;             // 0..63
        int colb = (c & 15) * 16;     // byte col 0..255
        int grow = row0 + row;
        if (grow >= N_NODES) grow = N_NODES - 1;
        uint4 v = *(const uint4*)((const char*)xb + (size_t)grow * 256 + colb);
        *(uint4*)(sxb + row * 256 + (colb ^ ((row & 7) << 4))) = v;
    }
    __syncthreads();

    f32x4 acc[2][4];
    #pragma unroll
    for (int m = 0; m < 2; ++m)
        #pragma unroll
        for (int n = 0; n < 4; ++n)
            acc[m][n] = f32x4{0.f, 0.f, 0.f, 0.f};

    #pragma unroll
    for (int n = 0; n < 4; ++n) {
        int row = n * 16 + l15;
        int rsw = (row & 7) << 4;
        #pragma unroll
        for (int s = 0; s < 4; ++s) {
            bf16x8 bh = *(const bf16x8*)(sxb + row * 256 + ((s * 64 + l4 * 16) ^ rsw));
            #pragma unroll
            for (int m = 0; m < 2; ++m) {
                acc[m][n] = __builtin_amdgcn_mfma_f32_16x16x32_bf16(Ah[m][s], bh, acc[m][n], 0, 0, 0);
                acc[m][n] = __builtin_amdgcn_mfma_f32_16x16x32_bf16(Al[m][s], bh, acc[m][n], 0, 0, 0);
            }
        }
    }

    // Epilogue: +bias, pack bf16, store (h padded to MPAD rows, unguarded)
    #pragma unroll
    for (int m = 0; m < 2; ++m) {
        f32x4 bias = *(const f32x4*)(b + c0 + m * 16 + l4 * 4);
        #pragma unroll
        for (int n = 0; n < 4; ++n) {
            int node = row0 + n * 16 + l15;
            f32x4 r = acc[m][n] + bias;
            uint2 packed;
            packed.x = (uint)f2bf(r[0]) | ((uint)f2bf(r[1]) << 16);
            packed.y = (uint)f2bf(r[2]) | ((uint)f2bf(r[3]) << 16);
            *(uint2*)(h + (size_t)node * HIDDEN + c0 + m * 16 + l4 * 4) = packed;
        }
    }
}

// ===========================================================================
// Fused CSR aggregation + leaky-relu + energy tap.
// 8-wide predicated gather rounds: 8 edge gathers in flight per round
// (invalid slots clamp to the node's last edge, weight forced to 0).
// LAST=0: write bf16 x for next GEMM. LAST=1: write f32 x to d_out.
// ===========================================================================
template <int LAST>
__global__ void agg_relu_tap(const ushort* __restrict__ h, const int* __restrict__ rowptr,
                             const int2* __restrict__ epack,
                             const float* __restrict__ We_l, const float* __restrict__ be_l,
                             const float* __restrict__ temp_l,
                             uint* __restrict__ xb, float* __restrict__ xout,
                             float* __restrict__ energy) {
    int gtid = blockIdx.x * blockDim.x + threadIdx.x;
    int n = gtid >> 6, lane = gtid & 63;
    if (n >= N_NODES) return;
    int j0 = rowptr[n], j1 = rowptr[n + 1];
    float2 acc = {0.f, 0.f};
    for (int jb = j0; jb < j1; jb += 8) {
        int srcs[8];
        float wk[8];
        uint u[8];
        #pragma unroll
        for (int k = 0; k < 8; ++k) {
            int jj = jb + k;
            bool valid = jj < j1;
            int slot = valid ? jj : j1 - 1;     // j1 >= 1 here (loop entered)
            int2 p = epack[slot];
            srcs[k] = p.x;
            wk[k] = valid ? __int_as_float(p.y) : 0.f;
        }
        #pragma unroll
        for (int k = 0; k < 8; ++k)
            u[k] = ((const uint*)(h + (size_t)srcs[k] * HIDDEN))[lane];
        #pragma unroll
        for (int k = 0; k < 8; ++k) {
            acc.x += __uint_as_float(u[k] << 16) * wk[k];
            acc.y += __uint_as_float(u[k] & 0xffff0000u) * wk[k];
        }
    }
    acc.x = acc.x > 0.f ? acc.x : 0.01f * acc.x;
    acc.y = acc.y > 0.f ? acc.y : 0.01f * acc.y;

    if (LAST) {
        ((float2*)(xout + (size_t)n * HIDDEN))[lane] = acc;
    } else {
        xb[(size_t)n * 64 + lane] = (uint)f2bf(acc.x) | ((uint)f2bf(acc.y) << 16);
    }

    float2 we2 = ((const float2*)We_l)[lane];
    float dot = acc.x * we2.x + acc.y * we2.y;
    #pragma unroll
    for (int off = 32; off > 0; off >>= 1) dot += __shfl_xor(dot, off);
    if (lane == 0) energy[n] += (dot + be_l[0]) * temp_l[0];
}

extern "C" void kernel_launch(void* const* d_in, const int* in_sizes, int n_in,
                              void* d_out, int out_size, void* d_ws, size_t ws_size,
                              hipStream_t stream) {
    const float* x    = (const float*)d_in[0];
    const int*   src  = (const int*)d_in[1];
    const int*   dst  = (const int*)d_in[2];
    const float* w    = (const float*)d_in[3];
    const float* Ws   = (const float*)d_in[4];
    const float* bs   = (const float*)d_in[5];
    const float* We   = (const float*)d_in[6];
    const float* be   = (const float*)d_in[7];
    const float* temp = (const float*)d_in[8];

    float* energy = (float*)d_out;            // [N]
    float* xout   = (float*)d_out + N_NODES;  // [N,128] f32 final x
    uint* xb = (uint*)xout;                   // bf16 x scratch aliases xout

    // workspace (epack placed right after h -> 16B aligned; cnt/fillc adjacent
    // for a single memset)
    ushort* h      = (ushort*)d_ws;                       // MPAD*128 bf16 (25.6MB)
    int2*   epack  = (int2*)(h + (size_t)MPAD * HIDDEN);  // E (8B each)
    int*    cnt    = (int*)(epack + N_EDGES);
    int*    fillc  = cnt + N_NODES;
    int*    excl   = fillc + N_NODES;
    int*    bsums  = excl + N_NODES;                      // 128
    int*    rowptr = bsums + 128;                         // N+1
    ushort* whi    = (ushort*)(rowptr + N_NODES + 4);     // 4*128*128
    ushort* wlo    = whi + N_LAYERS * HIDDEN * HIDDEN;

    // ---- zero cnt+fillc in one shot ----
    hipMemsetAsync(cnt, 0, 2 * N_NODES * sizeof(int), stream);

    // ---- fused prologue: tap0+cast | count_dst | prep_w ----
    prologue<<<TAP0_BLOCKS + CNT_BLOCKS + PREPW_BLOCKS, 256, 0, stream>>>(
        x, We, be, temp, energy, xb, dst, cnt, Ws, whi, wlo);

    // ---- scan -> rowptr, then CSR fill ----
    int nblk = (N_NODES + 1023) / 1024;
    scan1<<<nblk, 256, 0, stream>>>(cnt, excl, bsums, N_NODES);
    scan2<<<1, 256, 0, stream>>>(bsums, nblk);
    scan3<<<(N_NODES + 1 + 255) / 256, 256, 0, stream>>>(excl, bsums, rowptr, N_NODES);
    fill_csr<<<(N_EDGES + 255) / 256, 256, 0, stream>>>(src, dst, w, rowptr, fillc, epack);

    // ---- layers ----
    for (int i = 0; i < N_LAYERS; ++i) {
        gemm_lds<<<(MPAD / 64), 256, 0, stream>>>(
            xb, whi + (size_t)i * HIDDEN * HIDDEN,
            wlo + (size_t)i * HIDDEN * HIDDEN, bs + (size_t)i * HIDDEN, h);
        if (i < N_LAYERS - 1) {
            agg_relu_tap<0><<<(N_NODES * 64) / 256, 256, 0, stream>>>(
                h, rowptr, epack, We + (size_t)(i + 1) * HIDDEN, be + (i + 1),
                temp + (i + 1), xb, xout, energy);
        } else {
            agg_relu_tap<1><<<(N_NODES * 64) / 256, 256, 0, stream>>>(
                h, rowptr, epack, We + (size_t)(i + 1) * HIDDEN, be + (i + 1),
                temp + (i + 1), xb, xout, energy);
        }
    }
}

// Round 8
// 308.486 us; speedup vs baseline: 24.8875x; 1.2183x over previous
//
#include <hip/hip_runtime.h>
#include <hip/hip_bf16.h>

#define N_NODES 100000
#define N_EDGES 600000
#define HIDDEN 128
#define N_LAYERS 4
#define MPAD 100096   // N_NODES rounded up to 128 (and to 64)

#define TAP0_BLOCKS ((N_NODES * 64) / 256)                       // 25000
#define CNT_BLOCKS ((N_EDGES + 255) / 256)                       // 2344
#define PREPW_BLOCKS ((N_LAYERS * HIDDEN * HIDDEN + 255) / 256)  // 256

typedef short bf16x8 __attribute__((ext_vector_type(8)));
typedef float f32x4 __attribute__((ext_vector_type(4)));

__device__ inline ushort f2bf(float f) {
    __hip_bfloat16 h = __float2bfloat16(f);
    return *reinterpret_cast<ushort*>(&h);
}

__device__ inline float bfhi(uint u) { return __uint_as_float(u << 16); }
__device__ inline float bflo(uint u) { return __uint_as_float(u & 0xffff0000u); }

// ===========================================================================
// Prologue (fused independent prep): tap0+cast x0 | count_dst | prep_w
// ===========================================================================
__global__ void prologue(const float* __restrict__ x, const float* __restrict__ We,
                         const float* __restrict__ be, const float* __restrict__ temp,
                         float* __restrict__ energy, uint* __restrict__ xb,
                         const int* __restrict__ dst, int* __restrict__ cnt,
                         const float* __restrict__ Ws, ushort* __restrict__ whi,
                         ushort* __restrict__ wlo) {
    int b = blockIdx.x;
    if (b < TAP0_BLOCKS) {
        // --- tap0 + cast x0 -> bf16 (one wave per node) ---
        int gtid = b * 256 + threadIdx.x;
        int n = gtid >> 6, lane = gtid & 63;
        float2 v = ((const float2*)(x + (size_t)n * HIDDEN))[lane];
        xb[(size_t)n * 64 + lane] = (uint)f2bf(v.x) | ((uint)f2bf(v.y) << 16);
        float2 we2 = ((const float2*)We)[lane];
        float dot = v.x * we2.x + v.y * we2.y;
        #pragma unroll
        for (int off = 32; off > 0; off >>= 1) dot += __shfl_xor(dot, off);
        if (lane == 0) energy[n] = (dot + be[0]) * temp[0];
    } else if (b < TAP0_BLOCKS + CNT_BLOCKS) {
        // --- count dst degree ---
        int e = (b - TAP0_BLOCKS) * 256 + threadIdx.x;
        if (e < N_EDGES) atomicAdd(&cnt[dst[e]], 1);
    } else {
        // --- weight split: whi/wlo[l][c][k] = split_bf16(Ws[l][k][c]) ---
        int idx = (b - TAP0_BLOCKS - CNT_BLOCKS) * 256 + threadIdx.x;
        if (idx < N_LAYERS * HIDDEN * HIDDEN) {
            int l = idx >> 14;
            int r = idx & 16383;
            int c = r >> 7, k = r & 127;
            float v = Ws[(l << 14) + k * HIDDEN + c];
            ushort hi = f2bf(v);
            float hif = __uint_as_float(((uint)hi) << 16);
            whi[idx] = hi;
            wlo[idx] = f2bf(v - hif);
        }
    }
}

// ===========================================================================
// Exclusive scan (3 passes) over cnt -> rowptr
// ===========================================================================
__global__ void scan1(const int* __restrict__ cnt, int* __restrict__ excl,
                      int* __restrict__ bsums, int n) {
    __shared__ int lds[8];
    int t = threadIdx.x;
    int base = blockIdx.x * 1024 + t * 4;
    int v0 = (base + 0 < n) ? cnt[base + 0] : 0;
    int v1 = (base + 1 < n) ? cnt[base + 1] : 0;
    int v2 = (base + 2 < n) ? cnt[base + 2] : 0;
    int v3 = (base + 3 < n) ? cnt[base + 3] : 0;
    int tsum = v0 + v1 + v2 + v3;
    int lane = t & 63, wv = t >> 6;
    int s = tsum;
    #pragma unroll
    for (int off = 1; off < 64; off <<= 1) {
        int u = __shfl_up(s, off);
        if (lane >= off) s += u;
    }
    if (lane == 63) lds[wv] = s;
    __syncthreads();
    if (t == 0) {
        int a = 0;
        #pragma unroll
        for (int i = 0; i < 4; ++i) { int bb = lds[i]; lds[i] = a; a += bb; }
        lds[4] = a;
    }
    __syncthreads();
    int excl_t = (s - tsum) + lds[wv];
    if (base + 0 < n) excl[base + 0] = excl_t;
    if (base + 1 < n) excl[base + 1] = excl_t + v0;
    if (base + 2 < n) excl[base + 2] = excl_t + v0 + v1;
    if (base + 3 < n) excl[base + 3] = excl_t + v0 + v1 + v2;
    if (t == 0) bsums[blockIdx.x] = lds[4];
}

__global__ void scan2(int* __restrict__ bsums, int nb) {
    __shared__ int wsum[4];
    int t = threadIdx.x;
    int v = (t < nb) ? bsums[t] : 0;
    int lane = t & 63, wv = t >> 6;
    int s = v;
    #pragma unroll
    for (int off = 1; off < 64; off <<= 1) {
        int u = __shfl_up(s, off);
        if (lane >= off) s += u;
    }
    if (lane == 63) wsum[wv] = s;
    __syncthreads();
    int add = 0;
    for (int i = 0; i < wv; ++i) add += wsum[i];
    if (t < nb) bsums[t] = (s - v) + add;
}

__global__ void scan3(const int* __restrict__ excl, const int* __restrict__ bsums,
                      int* __restrict__ rowptr, int n) {
    int i = blockIdx.x * blockDim.x + threadIdx.x;
    if (i < n) rowptr[i] = excl[i] + bsums[i >> 10];
    else if (i == n) rowptr[n] = N_EDGES;
}

__global__ void fill_csr(const int* __restrict__ src, const int* __restrict__ dst,
                         const float* __restrict__ w, const int* __restrict__ rowptr,
                         int* __restrict__ fillc, int2* __restrict__ epack) {
    int e = blockIdx.x * blockDim.x + threadIdx.x;
    if (e >= N_EDGES) return;
    int d = dst[e];
    int pos = atomicAdd(&fillc[d], 1);
    int slot = rowptr[d] + pos;
    epack[slot] = make_int2(src[e], __float_as_int(w[e]));
}

// ===========================================================================
// LDS-staged MFMA GEMM: x plain bf16, W split (2 products Whi*x + Wlo*x).
// Block: 256 thr / 4 waves; tile = 64 nodes x 128 cols; LDS 16 KB,
// XOR-swizzled (col16B ^= (row&7)) -> conflict-free ds_read_b128.
// ===========================================================================
__global__ __launch_bounds__(256) void gemm_lds(
    const uint* __restrict__ xb,
    const ushort* __restrict__ whi, const ushort* __restrict__ wlo,
    const float* __restrict__ b, ushort* __restrict__ h) {
    __shared__ uint4 sx4[1024];          // 16 KB
    char* sxb = (char*)sx4;
    int t = threadIdx.x;
    int lane = t & 63, wv = t >> 6;
    int l15 = lane & 15, l4 = lane >> 4;
    int row0 = blockIdx.x * 64;
    int c0 = wv * 32;

    // A fragments (W side), global (L1-hot), hoisted before staging
    bf16x8 Ah[2][4], Al[2][4];
    #pragma unroll
    for (int m = 0; m < 2; ++m) {
        int c = c0 + m * 16 + l15;
        #pragma unroll
        for (int s = 0; s < 4; ++s) {
            int off = c * HIDDEN + s * 32 + l4 * 8;
            Ah[m][s] = *(const bf16x8*)(whi + off);
            Al[m][s] = *(const bf16x8*)(wlo + off);
        }
    }

    // Stage x tile: 1024 16B-chunks; thread t takes chunks j*256+t
    #pragma unroll
    for (int j = 0; j < 4; ++j) {
        int c = j * 256 + t;          // chunk index in [0,1024)
        int row = c >> 4;             // 0..63
        int colb = (c & 15) * 16;     // byte col 0..255
        int grow = row0 + row;
        if (grow >= N_NODES) grow = N_NODES - 1;
        uint4 v = *(const uint4*)((const char*)xb + (size_t)grow * 256 + colb);
        *(uint4*)(sxb + row * 256 + (colb ^ ((row & 7) << 4))) = v;
    }
    __syncthreads();

    f32x4 acc[2][4];
    #pragma unroll
    for (int m = 0; m < 2; ++m)
        #pragma unroll
        for (int n = 0; n < 4; ++n)
            acc[m][n] = f32x4{0.f, 0.f, 0.f, 0.f};

    #pragma unroll
    for (int n = 0; n < 4; ++n) {
        int row = n * 16 + l15;
        int rsw = (row & 7) << 4;
        #pragma unroll
        for (int s = 0; s < 4; ++s) {
            bf16x8 bh = *(const bf16x8*)(sxb + row * 256 + ((s * 64 + l4 * 16) ^ rsw));
            #pragma unroll
            for (int m = 0; m < 2; ++m) {
                acc[m][n] = __builtin_amdgcn_mfma_f32_16x16x32_bf16(Ah[m][s], bh, acc[m][n], 0, 0, 0);
                acc[m][n] = __builtin_amdgcn_mfma_f32_16x16x32_bf16(Al[m][s], bh, acc[m][n], 0, 0, 0);
            }
        }
    }

    // Epilogue: +bias, pack bf16, store (h padded to MPAD rows, unguarded)
    #pragma unroll
    for (int m = 0; m < 2; ++m) {
        f32x4 bias = *(const f32x4*)(b + c0 + m * 16 + l4 * 4);
        #pragma unroll
        for (int n = 0; n < 4; ++n) {
            int node = row0 + n * 16 + l15;
            f32x4 r = acc[m][n] + bias;
            uint2 packed;
            packed.x = (uint)f2bf(r[0]) | ((uint)f2bf(r[1]) << 16);
            packed.y = (uint)f2bf(r[2]) | ((uint)f2bf(r[3]) << 16);
            *(uint2*)(h + (size_t)node * HIDDEN + c0 + m * 16 + l4 * 4) = packed;
        }
    }
}

// ===========================================================================
// Fused CSR aggregation + leaky-relu + energy tap.
// 16 lanes per node (4 nodes per wave): lane loads 16B (uint4) of the row
// -> 4x fewer load instrs and 4 independent rows in flight per wave.
// Exact-width gather rounds (4/2/1) - no padded requests (round-7 lesson).
// LAST=0: write bf16 x (uint4, coalesced). LAST=1: write f32 x to d_out.
// ===========================================================================
template <int LAST>
__global__ void agg_relu_tap(const ushort* __restrict__ h, const int* __restrict__ rowptr,
                             const int2* __restrict__ epack,
                             const float* __restrict__ We_l, const float* __restrict__ be_l,
                             const float* __restrict__ temp_l,
                             uint* __restrict__ xb, float* __restrict__ xout,
                             float* __restrict__ energy) {
    int gtid = blockIdx.x * blockDim.x + threadIdx.x;
    int n = gtid >> 4;          // one 16-lane group per node
    int l16 = gtid & 15;
    if (n >= N_NODES) return;
    int j0 = rowptr[n], j1 = rowptr[n + 1];

    float a0 = 0.f, a1 = 0.f, a2 = 0.f, a3 = 0.f;
    float a4 = 0.f, a5 = 0.f, a6 = 0.f, a7 = 0.f;
    const char* hrow = (const char*)h;
    int cb = l16 * 16;          // byte offset of this lane's 16B chunk

    int j = j0;
    for (; j + 4 <= j1; j += 4) {
        int2 p0 = epack[j], p1 = epack[j + 1], p2 = epack[j + 2], p3 = epack[j + 3];
        uint4 u0 = *(const uint4*)(hrow + (size_t)p0.x * 256 + cb);
        uint4 u1 = *(const uint4*)(hrow + (size_t)p1.x * 256 + cb);
        uint4 u2 = *(const uint4*)(hrow + (size_t)p2.x * 256 + cb);
        uint4 u3 = *(const uint4*)(hrow + (size_t)p3.x * 256 + cb);
        float w0 = __int_as_float(p0.y), w1 = __int_as_float(p1.y);
        float w2 = __int_as_float(p2.y), w3 = __int_as_float(p3.y);
        a0 += bfhi(u0.x) * w0 + bfhi(u1.x) * w1 + bfhi(u2.x) * w2 + bfhi(u3.x) * w3;
        a1 += bflo(u0.x) * w0 + bflo(u1.x) * w1 + bflo(u2.x) * w2 + bflo(u3.x) * w3;
        a2 += bfhi(u0.y) * w0 + bfhi(u1.y) * w1 + bfhi(u2.y) * w2 + bfhi(u3.y) * w3;
        a3 += bflo(u0.y) * w0 + bflo(u1.y) * w1 + bflo(u2.y) * w2 + bflo(u3.y) * w3;
        a4 += bfhi(u0.z) * w0 + bfhi(u1.z) * w1 + bfhi(u2.z) * w2 + bfhi(u3.z) * w3;
        a5 += bflo(u0.z) * w0 + bflo(u1.z) * w1 + bflo(u2.z) * w2 + bflo(u3.z) * w3;
        a6 += bfhi(u0.w) * w0 + bfhi(u1.w) * w1 + bfhi(u2.w) * w2 + bfhi(u3.w) * w3;
        a7 += bflo(u0.w) * w0 + bflo(u1.w) * w1 + bflo(u2.w) * w2 + bflo(u3.w) * w3;
    }
    if (j + 2 <= j1) {
        int2 p0 = epack[j], p1 = epack[j + 1];
        uint4 u0 = *(const uint4*)(hrow + (size_t)p0.x * 256 + cb);
        uint4 u1 = *(const uint4*)(hrow + (size_t)p1.x * 256 + cb);
        float w0 = __int_as_float(p0.y), w1 = __int_as_float(p1.y);
        a0 += bfhi(u0.x) * w0 + bfhi(u1.x) * w1;
        a1 += bflo(u0.x) * w0 + bflo(u1.x) * w1;
        a2 += bfhi(u0.y) * w0 + bfhi(u1.y) * w1;
        a3 += bflo(u0.y) * w0 + bflo(u1.y) * w1;
        a4 += bfhi(u0.z) * w0 + bfhi(u1.z) * w1;
        a5 += bflo(u0.z) * w0 + bflo(u1.z) * w1;
        a6 += bfhi(u0.w) * w0 + bfhi(u1.w) * w1;
        a7 += bflo(u0.w) * w0 + bflo(u1.w) * w1;
        j += 2;
    }
    if (j < j1) {
        int2 p0 = epack[j];
        uint4 u0 = *(const uint4*)(hrow + (size_t)p0.x * 256 + cb);
        float w0 = __int_as_float(p0.y);
        a0 += bfhi(u0.x) * w0;
        a1 += bflo(u0.x) * w0;
        a2 += bfhi(u0.y) * w0;
        a3 += bflo(u0.y) * w0;
        a4 += bfhi(u0.z) * w0;
        a5 += bflo(u0.z) * w0;
        a6 += bfhi(u0.w) * w0;
        a7 += bflo(u0.w) * w0;
    }

    a0 = a0 > 0.f ? a0 : 0.01f * a0;
    a1 = a1 > 0.f ? a1 : 0.01f * a1;
    a2 = a2 > 0.f ? a2 : 0.01f * a2;
    a3 = a3 > 0.f ? a3 : 0.01f * a3;
    a4 = a4 > 0.f ? a4 : 0.01f * a4;
    a5 = a5 > 0.f ? a5 : 0.01f * a5;
    a6 = a6 > 0.f ? a6 : 0.01f * a6;
    a7 = a7 > 0.f ? a7 : 0.01f * a7;

    if (LAST) {
        float* orow = xout + (size_t)n * HIDDEN + l16 * 8;
        *(float4*)(orow + 0) = float4{a0, a1, a2, a3};
        *(float4*)(orow + 4) = float4{a4, a5, a6, a7};
    } else {
        uint4 packed;
        packed.x = (uint)f2bf(a0) | ((uint)f2bf(a1) << 16);
        packed.y = (uint)f2bf(a2) | ((uint)f2bf(a3) << 16);
        packed.z = (uint)f2bf(a4) | ((uint)f2bf(a5) << 16);
        packed.w = (uint)f2bf(a6) | ((uint)f2bf(a7) << 16);
        ((uint4*)(xb + (size_t)n * 64))[l16] = packed;
    }

    // energy tap: dot over this lane's 8 elems, reduce across the 16-lane group
    const float* wer = We_l + l16 * 8;
    float4 we0 = *(const float4*)(wer + 0);
    float4 we1 = *(const float4*)(wer + 4);
    float dot = a0 * we0.x + a1 * we0.y + a2 * we0.z + a3 * we0.w
              + a4 * we1.x + a5 * we1.y + a6 * we1.z + a7 * we1.w;
    #pragma unroll
    for (int off = 8; off > 0; off >>= 1) dot += __shfl_xor(dot, off);
    if (l16 == 0) energy[n] += (dot + be_l[0]) * temp_l[0];
}

extern "C" void kernel_launch(void* const* d_in, const int* in_sizes, int n_in,
                              void* d_out, int out_size, void* d_ws, size_t ws_size,
                              hipStream_t stream) {
    const float* x    = (const float*)d_in[0];
    const int*   src  = (const int*)d_in[1];
    const int*   dst  = (const int*)d_in[2];
    const float* w    = (const float*)d_in[3];
    const float* Ws   = (const float*)d_in[4];
    const float* bs   = (const float*)d_in[5];
    const float* We   = (const float*)d_in[6];
    const float* be   = (const float*)d_in[7];
    const float* temp = (const float*)d_in[8];

    float* energy = (float*)d_out;            // [N]
    float* xout   = (float*)d_out + N_NODES;  // [N,128] f32 final x
    uint* xb = (uint*)xout;                   // bf16 x scratch aliases xout

    // workspace (epack 16B-aligned after h; cnt/fillc adjacent for one memset)
    ushort* h      = (ushort*)d_ws;                       // MPAD*128 bf16 (25.6MB)
    int2*   epack  = (int2*)(h + (size_t)MPAD * HIDDEN);  // E (8B each)
    int*    cnt    = (int*)(epack + N_EDGES);
    int*    fillc  = cnt + N_NODES;
    int*    excl   = fillc + N_NODES;
    int*    bsums  = excl + N_NODES;                      // 128
    int*    rowptr = bsums + 128;                         // N+1
    ushort* whi    = (ushort*)(rowptr + N_NODES + 4);     // 4*128*128
    ushort* wlo    = whi + N_LAYERS * HIDDEN * HIDDEN;

    // ---- zero cnt+fillc in one shot ----
    hipMemsetAsync(cnt, 0, 2 * N_NODES * sizeof(int), stream);

    // ---- fused prologue: tap0+cast | count_dst | prep_w ----
    prologue<<<TAP0_BLOCKS + CNT_BLOCKS + PREPW_BLOCKS, 256, 0, stream>>>(
        x, We, be, temp, energy, xb, dst, cnt, Ws, whi, wlo);

    // ---- scan -> rowptr, then CSR fill ----
    int nblk = (N_NODES + 1023) / 1024;
    scan1<<<nblk, 256, 0, stream>>>(cnt, excl, bsums, N_NODES);
    scan2<<<1, 256, 0, stream>>>(bsums, nblk);
    scan3<<<(N_NODES + 1 + 255) / 256, 256, 0, stream>>>(excl, bsums, rowptr, N_NODES);
    fill_csr<<<(N_EDGES + 255) / 256, 256, 0, stream>>>(src, dst, w, rowptr, fillc, epack);

    // ---- layers ----
    int agg_blocks = (N_NODES * 16 + 255) / 256;   // 16 lanes per node
    for (int i = 0; i < N_LAYERS; ++i) {
        gemm_lds<<<(MPAD / 64), 256, 0, stream>>>(
            xb, whi + (size_t)i * HIDDEN * HIDDEN,
            wlo + (size_t)i * HIDDEN * HIDDEN, bs + (size_t)i * HIDDEN, h);
        if (i < N_LAYERS - 1) {
            agg_relu_tap<0><<<agg_blocks, 256, 0, stream>>>(
                h, rowptr, epack, We + (size_t)(i + 1) * HIDDEN, be + (i + 1),
                temp + (i + 1), xb, xout, energy);
        } else {
            agg_relu_tap<1><<<agg_blocks, 256, 0, stream>>>(
                h, rowptr, epack, We + (size_t)(i + 1) * HIDDEN, be + (i + 1),
                temp + (i + 1), xb, xout, energy);
        }
    }
}